// Round 1
// baseline (428.800 us; speedup 1.0000x reference)
//
#include <hip/hip_runtime.h>
#include <math.h>

// Problem constants (fixed-size problem)
#define NN   2048         // nodes
#define FB   4            // feature-batch dim F
#define DD   256          // d_model
#define EE   65536        // edges
#define NT   (NN*FB)      // tokens = 8192
#define FFD  2048         // transformer FF dim

// ---------------- static device scratch ----------------
__device__ float g_A[768], g_B[768];          // qkv rank-1 coefficients
__device__ float g_coefA[4], g_coefC[4];      // per-head softmax scalars
__device__ float g_Pv[4*DD];                  // out_w @ Av per head
__device__ float g_C0[DD];                    // lin_b + out_w@Bv + out_b
__device__ float g_meanv[6], g_G[36];         // subspace mean vector + Gram
__device__ float g_Vx[8*DD];                  // x1 basis vectors
__device__ float g_W1V[FFD*8];                // W1 @ Vx  (FFN1 collapsed to K=8)
__device__ float g_m[NT*4];                   // softmax-weighted feature means
__device__ float g_x1[NT*DD];
__device__ float g_h1[(size_t)NT*FFD];
__device__ float g_ff[NT*DD];
__device__ float g_xm[NN*DD];
__device__ float g_hs[NN*512];
__device__ float g_xg[NN*512];
__device__ int   g_deg[NN], g_off[NN+1], g_cur[NN], g_adj[EE];
__device__ float g_dinv[NN];

// ---------------- helpers ----------------
__device__ __forceinline__ float blk_sum256(float v, float* red) {
  #pragma unroll
  for (int o = 32; o > 0; o >>= 1) v += __shfl_down(v, o, 64);
  int lane = threadIdx.x & 63, w = threadIdx.x >> 6;
  __syncthreads();
  if (lane == 0) red[w] = v;
  __syncthreads();
  return red[0] + red[1] + red[2] + red[3];
}

// ---------------- K1: A[j] = ipw[j,:]·L ; B[j] = ipw[j,:]·lb + ipb[j] ----------------
__global__ __launch_bounds__(256) void k_prep_ab(const float* __restrict__ ipw,
    const float* __restrict__ ipb, const float* __restrict__ linw,
    const float* __restrict__ linb) {
  int j = blockIdx.x * 256 + threadIdx.x;
  if (j >= 768) return;
  float a = 0.f, b = 0.f;
  for (int d = 0; d < 256; d++) {
    float w = ipw[j * 256 + d];
    a += w * linw[d];
    b += w * linb[d];
  }
  g_A[j] = a;
  g_B[j] = b + ipb[j];
}

// ---------------- K2: head scalars, Pv, C0, Gram, basis Vx ----------------
__global__ __launch_bounds__(256) void k_prep_head(const float* __restrict__ outw,
    const float* __restrict__ outb, const float* __restrict__ linw,
    const float* __restrict__ linb, const float* __restrict__ g1,
    const float* __restrict__ b1ln) {
  __shared__ float red[4];
  int t = threadIdx.x, lane = t & 63, w = t >> 6;
  // per-head scalars: wave w handles head w
  {
    float aq = g_A[w*64 + lane], ak = g_A[256 + w*64 + lane], bq = g_B[w*64 + lane];
    float pa = aq * ak, pc = bq * ak;
    #pragma unroll
    for (int o = 32; o > 0; o >>= 1) { pa += __shfl_down(pa, o, 64); pc += __shfl_down(pc, o, 64); }
    if (lane == 0) { g_coefA[w] = pa * 0.125f; g_coefC[w] = pc * 0.125f; }
  }
  // Pv[h][d], Q0[d], C0[d]  (thread t == dim d)
  int d = t;
  float pv[4];
  for (int h = 0; h < 4; h++) {
    float sv = 0.f;
    for (int u = 0; u < 64; u++) sv += outw[d*256 + h*64 + u] * g_A[512 + h*64 + u];
    pv[h] = sv;
  }
  float q0 = 0.f;
  for (int e = 0; e < 256; e++) q0 += outw[d*256 + e] * g_B[512 + e];
  q0 += outb[d];
  float c0 = linb[d] + q0;
  for (int h = 0; h < 4; h++) g_Pv[h*256 + d] = pv[h];
  g_C0[d] = c0;
  // subspace vectors M = {L, Pv0..3, C0}; mean + Gram
  float Mv[6] = { linw[d], pv[0], pv[1], pv[2], pv[3], c0 };
  for (int k = 0; k < 6; k++) {
    float s = blk_sum256(Mv[k], red);
    if (t == 0) g_meanv[k] = s * (1.f/256.f);
  }
  for (int k = 0; k < 6; k++)
    for (int l = k; l < 6; l++) {
      float s = blk_sum256(Mv[k] * Mv[l], red);
      if (t == 0) { g_G[k*6+l] = s; g_G[l*6+k] = s; }
    }
  // x1 basis: Vx_k = M_k*g (k<6), Vx6 = g (the -mu direction), Vx7 = ln1_b
  for (int k = 0; k < 6; k++) g_Vx[k*256 + d] = Mv[k] * g1[d];
  g_Vx[6*256 + d] = g1[d];
  g_Vx[7*256 + d] = b1ln[d];
}

// ---------------- K2c: W1V[j][k] = W1[j,:]·Vx_k ----------------
__global__ __launch_bounds__(256) void k_w1v(const float* __restrict__ w1) {
  __shared__ float vx[8][256];
  int t = threadIdx.x;
  for (int k = 0; k < 8; k++) vx[k][t] = g_Vx[k*256 + t];
  __syncthreads();
  int j = blockIdx.x * 256 + t;
  float acc[8] = {0,0,0,0,0,0,0,0};
  for (int d = 0; d < 256; d++) {
    float w = w1[j*256 + d];
    #pragma unroll
    for (int k = 0; k < 8; k++) acc[k] += w * vx[k][d];
  }
  #pragma unroll
  for (int k = 0; k < 8; k++) g_W1V[j*8 + k] = acc[k];
}

// ---------------- K3: m[n,f,h] = sum_j e^{t*fj} fj / sum_j e^{t*fj} ----------------
__global__ __launch_bounds__(256) void k_attn_m(const float* __restrict__ feat) {
  __shared__ float fs[4][2048];
  __shared__ float ss[64][4], ww[64][4];
  int t = threadIdx.x;
  for (int i = t; i < 2048; i += 256) {
    const float4 v = *(const float4*)&feat[i*4];
    fs[0][i] = v.x; fs[1][i] = v.y; fs[2][i] = v.z; fs[3][i] = v.w;
  }
  __syncthreads();
  int tuple = blockIdx.x * 64 + (t >> 2);
  int c = t & 3;
  int h = tuple & 3, f = (tuple >> 2) & 3, n = tuple >> 4;
  float fi = fs[f][n];
  float tt = g_coefA[h] * fi + g_coefC[h];
  float s = 0.f, wsum = 0.f;
  int j0 = c * 512;
  for (int j = j0; j < j0 + 512; j++) {
    float fj = fs[f][j];
    float e = __expf(tt * fj);
    s += e; wsum += e * fj;
  }
  ss[t>>2][c] = s; ww[t>>2][c] = wsum;
  __syncthreads();
  if (c == 0) {
    float S = ss[t>>2][0] + ss[t>>2][1] + ss[t>>2][2] + ss[t>>2][3];
    float W = ww[t>>2][0] + ww[t>>2][1] + ww[t>>2][2] + ww[t>>2][3];
    g_m[tuple] = W / S;
  }
}

// ---------------- K4: per-token LN1 coefficients -> x1, h1 ----------------
__global__ __launch_bounds__(256) void k_token(const float* __restrict__ feat,
                                               const float* __restrict__ fb1) {
  __shared__ float vx[8][256];
  __shared__ float cc[16][8];
  int t = threadIdx.x;
  for (int k = 0; k < 8; k++) vx[k][t] = g_Vx[k*256 + t];
  if (t < 16) {
    int tok = blockIdx.x * 16 + t;
    int n = tok >> 2, f = tok & 3;
    float fi = feat[n*4 + f];
    float u[6] = { fi, g_m[tok*4+0], g_m[tok*4+1], g_m[tok*4+2], g_m[tok*4+3], 1.f };
    float mu = 0.f;
    #pragma unroll
    for (int k = 0; k < 6; k++) mu += g_meanv[k] * u[k];
    float q = 0.f;
    for (int k = 0; k < 6; k++)
      for (int l = 0; l < 6; l++) q += u[k] * g_G[k*6+l] * u[l];
    q *= (1.f/256.f);
    float var = q - mu * mu;
    float s = rsqrtf(var + 1e-5f);
    cc[t][0] = fi * s; cc[t][1] = u[1]*s; cc[t][2] = u[2]*s; cc[t][3] = u[3]*s;
    cc[t][4] = u[4]*s; cc[t][5] = s; cc[t][6] = -mu*s; cc[t][7] = 1.f;
  }
  __syncthreads();
  int tok0 = blockIdx.x * 16;
  // x1 = sum_k c_k Vx_k
  for (int tt2 = 0; tt2 < 16; tt2++) {
    float v = 0.f;
    #pragma unroll
    for (int k = 0; k < 8; k++) v += cc[tt2][k] * vx[k][t];
    g_x1[(tok0 + tt2)*256 + t] = v;
  }
  // h1 = relu(sum_k c_k W1V[j,k] + b1[j])  -- vectorized 4 j's per thread
  for (int jj = 0; jj < 2; jj++) {
    int j0 = jj * 1024 + t * 4;
    float4 w0[4], w1[4];
    #pragma unroll
    for (int qj = 0; qj < 4; qj++) {
      w0[qj] = *(const float4*)&g_W1V[(j0+qj)*8];
      w1[qj] = *(const float4*)&g_W1V[(j0+qj)*8 + 4];
    }
    const float4 bb = *(const float4*)&fb1[j0];
    for (int tt2 = 0; tt2 < 16; tt2++) {
      float c0=cc[tt2][0], c1=cc[tt2][1], c2=cc[tt2][2], c3=cc[tt2][3];
      float c4=cc[tt2][4], c5=cc[tt2][5], c6=cc[tt2][6], c7=cc[tt2][7];
      float4 hv;
      hv.x = bb.x + c0*w0[0].x + c1*w0[0].y + c2*w0[0].z + c3*w0[0].w
                  + c4*w1[0].x + c5*w1[0].y + c6*w1[0].z + c7*w1[0].w;
      hv.y = bb.y + c0*w0[1].x + c1*w0[1].y + c2*w0[1].z + c3*w0[1].w
                  + c4*w1[1].x + c5*w1[1].y + c6*w1[1].z + c7*w1[1].w;
      hv.z = bb.z + c0*w0[2].x + c1*w0[2].y + c2*w0[2].z + c3*w0[2].w
                  + c4*w1[2].x + c5*w1[2].y + c6*w1[2].z + c7*w1[2].w;
      hv.w = bb.w + c0*w0[3].x + c1*w0[3].y + c2*w0[3].z + c3*w0[3].w
                  + c4*w1[3].x + c5*w1[3].y + c6*w1[3].z + c7*w1[3].w;
      hv.x = fmaxf(hv.x, 0.f); hv.y = fmaxf(hv.y, 0.f);
      hv.z = fmaxf(hv.z, 0.f); hv.w = fmaxf(hv.w, 0.f);
      *(float4*)&g_h1[(size_t)(tok0 + tt2)*2048 + j0] = hv;
    }
  }
}

// ---------------- generic fp32 tiled GEMM: C[M,N] = (rs∘A)[M,K] @ Bt[N,K]^T ----------------
__global__ __launch_bounds__(256) void k_gemm(const float* __restrict__ A,
    const float* __restrict__ Bt, float* __restrict__ C, int M, int N, int K,
    const float* __restrict__ rowscale, const float* __restrict__ bias, int dorelu) {
  __shared__ float As[16][68];   // [k][m], stride 68 keeps float4 reads aligned + 2-way banks
  __shared__ float Bs[16][68];   // [k][n]
  const int tx = threadIdx.x & 15;
  const int ty = threadIdx.x >> 4;
  const int bm = blockIdx.y * 64;
  const int bn = blockIdx.x * 64;
  const int t  = threadIdx.x;
  const int lr = t >> 2;         // 0..63
  const int lk = (t & 3) << 2;   // 0,4,8,12
  float acc[4][4] = {{0.f}};
  for (int k0 = 0; k0 < K; k0 += 16) {
    float4 a4 = *(const float4*)&A[(size_t)(bm + lr) * K + k0 + lk];
    if (rowscale) { float rs = rowscale[bm + lr]; a4.x*=rs; a4.y*=rs; a4.z*=rs; a4.w*=rs; }
    float4 b4 = *(const float4*)&Bt[(size_t)(bn + lr) * K + k0 + lk];
    As[lk+0][lr]=a4.x; As[lk+1][lr]=a4.y; As[lk+2][lr]=a4.z; As[lk+3][lr]=a4.w;
    Bs[lk+0][lr]=b4.x; Bs[lk+1][lr]=b4.y; Bs[lk+2][lr]=b4.z; Bs[lk+3][lr]=b4.w;
    __syncthreads();
    #pragma unroll
    for (int k = 0; k < 16; k++) {
      const float4 av = *(const float4*)&As[k][ty*4];
      const float4 bv = *(const float4*)&Bs[k][tx*4];
      acc[0][0]+=av.x*bv.x; acc[0][1]+=av.x*bv.y; acc[0][2]+=av.x*bv.z; acc[0][3]+=av.x*bv.w;
      acc[1][0]+=av.y*bv.x; acc[1][1]+=av.y*bv.y; acc[1][2]+=av.y*bv.z; acc[1][3]+=av.y*bv.w;
      acc[2][0]+=av.z*bv.x; acc[2][1]+=av.z*bv.y; acc[2][2]+=av.z*bv.z; acc[2][3]+=av.z*bv.w;
      acc[3][0]+=av.w*bv.x; acc[3][1]+=av.w*bv.y; acc[3][2]+=av.w*bv.z; acc[3][3]+=av.w*bv.w;
    }
    __syncthreads();
  }
  #pragma unroll
  for (int i = 0; i < 4; i++) {
    int m = bm + ty*4 + i;
    #pragma unroll
    for (int j = 0; j < 4; j++) {
      int n = bn + tx*4 + j;
      float v = acc[i][j];
      if (bias) v += bias[n];
      if (dorelu) v = fmaxf(v, 0.f);
      C[(size_t)m * N + n] = v;
    }
  }
}

// ---------------- K6: x2 = LN2(x1+ff); xm = relu(mean over f) ----------------
__global__ __launch_bounds__(256) void k_ln2_mean(const float* __restrict__ g2,
                                                  const float* __restrict__ b2ln) {
  __shared__ float red[4];
  int n = blockIdx.x, t = threadIdx.x;
  float acc = 0.f;
  for (int f = 0; f < 4; f++) {
    int tok = n*4 + f;
    float v = g_x1[tok*256 + t] + g_ff[tok*256 + t];
    float s1 = blk_sum256(v, red);
    float s2 = blk_sum256(v*v, red);
    float mu = s1 * (1.f/256.f);
    float var = s2 * (1.f/256.f) - mu*mu;
    float x2 = (v - mu) * rsqrtf(var + 1e-5f) * g2[t] + b2ln[t];
    acc += x2;
  }
  g_xm[n*256 + t] = fmaxf(acc * 0.25f, 0.f);
}

// ---------------- GCN graph prep ----------------
__global__ __launch_bounds__(256) void k_zero() {
  int i = blockIdx.x * 256 + threadIdx.x;
  if (i < NN) { g_deg[i] = 0; g_cur[i] = 0; }
}
__global__ __launch_bounds__(256) void k_deg(const int* __restrict__ edges) {
  int e = blockIdx.x * 256 + threadIdx.x;
  if (e >= EE) return;
  atomicAdd(&g_deg[edges[EE + e]], 1);
}
__global__ __launch_bounds__(256) void k_scan() {
  int t = threadIdx.x;
  int base = t * 8;
  int v[8], ex[8], sum = 0;
  #pragma unroll
  for (int i = 0; i < 8; i++) { ex[i] = sum; v[i] = g_deg[base+i]; sum += v[i]; }
  int lane = t & 63, w = t >> 6;
  int inc = sum;
  #pragma unroll
  for (int o = 1; o < 64; o <<= 1) { int x = __shfl_up(inc, o, 64); if (lane >= o) inc += x; }
  __shared__ int wt[4];
  if (lane == 63) wt[w] = inc;
  __syncthreads();
  int wb = 0;
  for (int j = 0; j < w; j++) wb += wt[j];
  int excl = wb + inc - sum;
  #pragma unroll
  for (int i = 0; i < 8; i++) {
    g_off[base+i] = excl + ex[i];
    g_dinv[base+i] = rsqrtf((float)(v[i] + 1));
  }
  if (t == 255) g_off[NN] = wb + inc;
}
__global__ __launch_bounds__(256) void k_fill(const int* __restrict__ edges) {
  int e = blockIdx.x * 256 + threadIdx.x;
  if (e >= EE) return;
  int s = edges[e], d = edges[EE + e];
  int pos = atomicAdd(&g_cur[d], 1);
  g_adj[g_off[d] + pos] = s;
}

// ---------------- GCN aggregation: out[i] = dinv[i]*(hs[i] + sum_{s in N(i)} hs[s]) + b ----------------
__global__ __launch_bounds__(128) void k_agg(const float* __restrict__ bias,
                                             float* __restrict__ out, int dorelu) {
  int i = blockIdx.x, t = threadIdx.x;
  int d = t * 4;
  const float4 self = *(const float4*)&g_hs[i*512 + d];
  float a0 = self.x, a1 = self.y, a2 = self.z, a3 = self.w;
  int e0 = g_off[i], e1 = g_off[i+1];
  for (int e = e0; e < e1; e++) {
    int s = g_adj[e];
    const float4 v = *(const float4*)&g_hs[s*512 + d];
    a0 += v.x; a1 += v.y; a2 += v.z; a3 += v.w;
  }
  float di = g_dinv[i];
  a0 = di*a0 + bias[d+0]; a1 = di*a1 + bias[d+1];
  a2 = di*a2 + bias[d+2]; a3 = di*a3 + bias[d+3];
  if (dorelu) { a0=fmaxf(a0,0.f); a1=fmaxf(a1,0.f); a2=fmaxf(a2,0.f); a3=fmaxf(a3,0.f); }
  float4 r; r.x=a0; r.y=a1; r.z=a2; r.w=a3;
  *(float4*)&out[i*512 + d] = r;
}

// ---------------- host ----------------
static float* symf(const void* s) { void* p = nullptr; (void)hipGetSymbolAddress(&p, s); return (float*)p; }

extern "C" void kernel_launch(void* const* d_in, const int* in_sizes, int n_in,
                              void* d_out, int out_size, void* d_ws, size_t ws_size,
                              hipStream_t stream) {
  const float* feat = (const float*)d_in[0];
  const int*   edges= (const int*)  d_in[1];
  const float* linw = (const float*)d_in[2];
  const float* linb = (const float*)d_in[3];
  const float* ipw  = (const float*)d_in[4];
  const float* ipb  = (const float*)d_in[5];
  const float* outw = (const float*)d_in[6];
  const float* outb = (const float*)d_in[7];
  const float* ln1g = (const float*)d_in[8];
  const float* ln1b = (const float*)d_in[9];
  const float* fw1  = (const float*)d_in[10];
  const float* fb1  = (const float*)d_in[11];
  const float* fw2  = (const float*)d_in[12];
  const float* fb2  = (const float*)d_in[13];
  const float* ln2g = (const float*)d_in[14];
  const float* ln2b = (const float*)d_in[15];
  const float* W1g  = (const float*)d_in[16];
  const float* b1g  = (const float*)d_in[17];
  const float* W2g  = (const float*)d_in[18];
  const float* b2g  = (const float*)d_in[19];
  const float* W3g  = (const float*)d_in[20];
  const float* b3g  = (const float*)d_in[21];
  const float* W4g  = (const float*)d_in[22];
  const float* b4g  = (const float*)d_in[23];
  float* out = (float*)d_out;

  float* p_h1  = symf(HIP_SYMBOL(g_h1));
  float* p_ff  = symf(HIP_SYMBOL(g_ff));
  float* p_xm  = symf(HIP_SYMBOL(g_xm));
  float* p_hs  = symf(HIP_SYMBOL(g_hs));
  float* p_xg  = symf(HIP_SYMBOL(g_xg));
  float* p_dinv= symf(HIP_SYMBOL(g_dinv));

  // transformer (collapsed via rank-1 embedding)
  k_prep_ab  <<<3, 256, 0, stream>>>(ipw, ipb, linw, linb);
  k_prep_head<<<1, 256, 0, stream>>>(outw, outb, linw, linb, ln1g, ln1b);
  k_w1v      <<<8, 256, 0, stream>>>(fw1);
  k_attn_m   <<<512, 256, 0, stream>>>(feat);
  k_token    <<<512, 256, 0, stream>>>(feat, fb1);
  // FFN2: ff = h1 @ W2^T + b2
  k_gemm<<<dim3(256/64, NT/64), 256, 0, stream>>>(p_h1, fw2, p_ff, NT, 256, 2048,
                                                  nullptr, fb2, 0);
  k_ln2_mean<<<NN, 256, 0, stream>>>(ln2g, ln2b);

  // GCN graph prep (CSR by dst)
  k_zero<<<8, 256, 0, stream>>>();
  k_deg <<<EE/256, 256, 0, stream>>>(edges);
  k_scan<<<1, 256, 0, stream>>>();
  k_fill<<<EE/256, 256, 0, stream>>>(edges);

  // GCN layers: hs = (dinv∘x) @ W^T ; out = dinv*(self+neighbors) + b ; relu(1-3)
  k_gemm<<<dim3(512/64, NN/64), 256, 0, stream>>>(p_xm, W1g, p_hs, NN, 512, 256,
                                                  p_dinv, nullptr, 0);
  k_agg<<<NN, 128, 0, stream>>>(b1g, p_xg, 1);
  k_gemm<<<dim3(512/64, NN/64), 256, 0, stream>>>(p_xg, W2g, p_hs, NN, 512, 512,
                                                  p_dinv, nullptr, 0);
  k_agg<<<NN, 128, 0, stream>>>(b2g, p_xg, 1);
  k_gemm<<<dim3(512/64, NN/64), 256, 0, stream>>>(p_xg, W3g, p_hs, NN, 512, 512,
                                                  p_dinv, nullptr, 0);
  k_agg<<<NN, 128, 0, stream>>>(b3g, p_xg, 1);
  k_gemm<<<dim3(512/64, NN/64), 256, 0, stream>>>(p_xg, W4g, p_hs, NN, 512, 512,
                                                  p_dinv, nullptr, 0);
  k_agg<<<NN, 128, 0, stream>>>(b4g, out, 0);
}

// Round 2
// 312.606 us; speedup vs baseline: 1.3717x; 1.3717x over previous
//
#include <hip/hip_runtime.h>
#include <hip/hip_bf16.h>
#include <math.h>

// Problem constants
#define NN   2048
#define FB   4
#define DD   256
#define EE   65536
#define NT   (NN*FB)
#define FFD  2048

typedef unsigned int u32;
typedef unsigned short u16;
typedef __attribute__((ext_vector_type(4))) float f32x4;
typedef __attribute__((ext_vector_type(8))) short bf16x8;

// ---------------- static device scratch ----------------
__device__ float g_A[768], g_B[768];
__device__ float g_coefA[4], g_coefC[4];
__device__ float g_meanv[6], g_G[36];
__device__ float g_Vx[8*DD];
__device__ float g_W1V[FFD*8];
__device__ float g_m[NT*4];
__device__ float g_x1[NT*DD];
__device__ u16   g_h1h[(size_t)NT*FFD];     // h1 in bf16 (32 MB)
__device__ float g_ff[NT*DD];
__device__ u16   g_xmh[NN*DD];              // GCN input bf16
__device__ u16   g_hsh[NN*512];             // per-layer transformed (dinv-scaled) bf16
__device__ u16   g_xgh[NN*512];             // per-layer activations bf16
__device__ u16   g_w2h[DD*FFD];             // ffn_w2 bf16 [256][2048]
__device__ u16   g_wgh[131072 + 3*262144];  // W1..W4 bf16
__device__ int   g_deg[NN], g_off[NN+1], g_cur[NN], g_adj[EE];
__device__ float g_dinv[NN];

// ---------------- helpers ----------------
__device__ __forceinline__ u16 f2bf(float x) {
  u32 u = __float_as_uint(x);
  return (u16)((u + 0x7FFFu + ((u >> 16) & 1u)) >> 16);
}
__device__ __forceinline__ float bf2f(u16 x) {
  return __uint_as_float(((u32)x) << 16);
}
__device__ __forceinline__ void gl_lds16(const void* g, void* l) {
  __builtin_amdgcn_global_load_lds(
      (const __attribute__((address_space(1))) u32*)g,
      (__attribute__((address_space(3))) u32*)l, 16, 0, 0);
}
__device__ __forceinline__ float blk_sum256(float v, float* red) {
  #pragma unroll
  for (int o = 32; o > 0; o >>= 1) v += __shfl_down(v, o, 64);
  int lane = threadIdx.x & 63, w = threadIdx.x >> 6;
  __syncthreads();
  if (lane == 0) red[w] = v;
  __syncthreads();
  return red[0] + red[1] + red[2] + red[3];
}

// ---------------- K1: rank-1 qkv coefficients ----------------
__global__ __launch_bounds__(256) void k_prep_ab(const float* __restrict__ ipw,
    const float* __restrict__ ipb, const float* __restrict__ linw,
    const float* __restrict__ linb) {
  int j = blockIdx.x * 256 + threadIdx.x;
  if (j >= 768) return;
  float a = 0.f, b = 0.f;
  for (int d = 0; d < 256; d++) {
    float w = ipw[j * 256 + d];
    a += w * linw[d];
    b += w * linb[d];
  }
  g_A[j] = a;
  g_B[j] = b + ipb[j];
}

// ---------------- K2: head scalars, Gram, basis Vx ----------------
__global__ __launch_bounds__(256) void k_prep_head(const float* __restrict__ outw,
    const float* __restrict__ outb, const float* __restrict__ linw,
    const float* __restrict__ linb, const float* __restrict__ g1,
    const float* __restrict__ b1ln) {
  __shared__ float red[4];
  int t = threadIdx.x, lane = t & 63, w = t >> 6;
  {
    float aq = g_A[w*64 + lane], ak = g_A[256 + w*64 + lane], bq = g_B[w*64 + lane];
    float pa = aq * ak, pc = bq * ak;
    #pragma unroll
    for (int o = 32; o > 0; o >>= 1) { pa += __shfl_down(pa, o, 64); pc += __shfl_down(pc, o, 64); }
    if (lane == 0) { g_coefA[w] = pa * 0.125f; g_coefC[w] = pc * 0.125f; }
  }
  int d = t;
  float pv[4];
  for (int h = 0; h < 4; h++) {
    float sv = 0.f;
    for (int u = 0; u < 64; u++) sv += outw[d*256 + h*64 + u] * g_A[512 + h*64 + u];
    pv[h] = sv;
  }
  float q0 = 0.f;
  for (int e = 0; e < 256; e++) q0 += outw[d*256 + e] * g_B[512 + e];
  q0 += outb[d];
  float c0 = linb[d] + q0;
  float Mv[6] = { linw[d], pv[0], pv[1], pv[2], pv[3], c0 };
  for (int k = 0; k < 6; k++) {
    float s = blk_sum256(Mv[k], red);
    if (t == 0) g_meanv[k] = s * (1.f/256.f);
  }
  for (int k = 0; k < 6; k++)
    for (int l = k; l < 6; l++) {
      float s = blk_sum256(Mv[k] * Mv[l], red);
      if (t == 0) { g_G[k*6+l] = s; g_G[l*6+k] = s; }
    }
  for (int k = 0; k < 6; k++) g_Vx[k*256 + d] = Mv[k] * g1[d];
  g_Vx[6*256 + d] = g1[d];
  g_Vx[7*256 + d] = b1ln[d];
}

// ---------------- K2c: W1V[j][k] = W1[j,:]·Vx_k ----------------
__global__ __launch_bounds__(256) void k_w1v(const float* __restrict__ w1) {
  __shared__ float vx[8][256];
  int t = threadIdx.x;
  for (int k = 0; k < 8; k++) vx[k][t] = g_Vx[k*256 + t];
  __syncthreads();
  int j = blockIdx.x * 256 + t;
  float acc[8] = {0,0,0,0,0,0,0,0};
  for (int d = 0; d < 256; d++) {
    float w = w1[j*256 + d];
    #pragma unroll
    for (int k = 0; k < 8; k++) acc[k] += w * vx[k][d];
  }
  #pragma unroll
  for (int k = 0; k < 8; k++) g_W1V[j*8 + k] = acc[k];
}

// ---------------- cvt fp32 -> bf16 ----------------
__global__ __launch_bounds__(256) void k_cvt(const float* __restrict__ s,
                                             u16* __restrict__ d, int n) {
  int i = (blockIdx.x * 256 + threadIdx.x) * 4;
  if (i >= n) return;
  float4 v = *(const float4*)&s[i];
  ushort4 r;
  r.x = f2bf(v.x); r.y = f2bf(v.y); r.z = f2bf(v.z); r.w = f2bf(v.w);
  *(ushort4*)&d[i] = r;
}

// ---------------- K3: softmax-weighted feature means ----------------
__global__ __launch_bounds__(256) void k_attn_m(const float* __restrict__ feat) {
  __shared__ float fs[4][2048];
  __shared__ float ss[64][4], ww[64][4];
  int t = threadIdx.x;
  for (int i = t; i < 2048; i += 256) {
    const float4 v = *(const float4*)&feat[i*4];
    fs[0][i] = v.x; fs[1][i] = v.y; fs[2][i] = v.z; fs[3][i] = v.w;
  }
  __syncthreads();
  int tuple = blockIdx.x * 64 + (t >> 2);
  int c = t & 3;
  int h = tuple & 3, f = (tuple >> 2) & 3, n = tuple >> 4;
  float fi = fs[f][n];
  float tt = g_coefA[h] * fi + g_coefC[h];
  float s = 0.f, wsum = 0.f;
  int j0 = c * 512;
  for (int j = j0; j < j0 + 512; j++) {
    float fj = fs[f][j];
    float e = __expf(tt * fj);
    s += e; wsum += e * fj;
  }
  ss[t>>2][c] = s; ww[t>>2][c] = wsum;
  __syncthreads();
  if (c == 0) {
    float S = ss[t>>2][0] + ss[t>>2][1] + ss[t>>2][2] + ss[t>>2][3];
    float W = ww[t>>2][0] + ww[t>>2][1] + ww[t>>2][2] + ww[t>>2][3];
    g_m[tuple] = W / S;
  }
}

// ---------------- K4: per-token LN1 coeffs -> x1 (f32), h1 (bf16) ----------------
__global__ __launch_bounds__(256) void k_token(const float* __restrict__ feat,
                                               const float* __restrict__ fb1) {
  __shared__ float vx[8][256];
  __shared__ float cc[16][8];
  int t = threadIdx.x;
  for (int k = 0; k < 8; k++) vx[k][t] = g_Vx[k*256 + t];
  if (t < 16) {
    int tok = blockIdx.x * 16 + t;
    int n = tok >> 2, f = tok & 3;
    float fi = feat[n*4 + f];
    float u[6] = { fi, g_m[tok*4+0], g_m[tok*4+1], g_m[tok*4+2], g_m[tok*4+3], 1.f };
    float mu = 0.f;
    #pragma unroll
    for (int k = 0; k < 6; k++) mu += g_meanv[k] * u[k];
    float q = 0.f;
    for (int k = 0; k < 6; k++)
      for (int l = 0; l < 6; l++) q += u[k] * g_G[k*6+l] * u[l];
    q *= (1.f/256.f);
    float var = q - mu * mu;
    float s = rsqrtf(var + 1e-5f);
    cc[t][0] = fi * s; cc[t][1] = u[1]*s; cc[t][2] = u[2]*s; cc[t][3] = u[3]*s;
    cc[t][4] = u[4]*s; cc[t][5] = s; cc[t][6] = -mu*s; cc[t][7] = 1.f;
  }
  __syncthreads();
  int tok0 = blockIdx.x * 16;
  for (int tt2 = 0; tt2 < 16; tt2++) {
    float v = 0.f;
    #pragma unroll
    for (int k = 0; k < 8; k++) v += cc[tt2][k] * vx[k][t];
    g_x1[(tok0 + tt2)*256 + t] = v;
  }
  for (int jj = 0; jj < 2; jj++) {
    int j0 = jj * 1024 + t * 4;
    float4 w0[4], w1[4];
    #pragma unroll
    for (int qj = 0; qj < 4; qj++) {
      w0[qj] = *(const float4*)&g_W1V[(j0+qj)*8];
      w1[qj] = *(const float4*)&g_W1V[(j0+qj)*8 + 4];
    }
    const float4 bb = *(const float4*)&fb1[j0];
    for (int tt2 = 0; tt2 < 16; tt2++) {
      float c0=cc[tt2][0], c1=cc[tt2][1], c2=cc[tt2][2], c3=cc[tt2][3];
      float c4=cc[tt2][4], c5=cc[tt2][5], c6=cc[tt2][6], c7=cc[tt2][7];
      float4 hv;
      hv.x = bb.x + c0*w0[0].x + c1*w0[0].y + c2*w0[0].z + c3*w0[0].w
                  + c4*w1[0].x + c5*w1[0].y + c6*w1[0].z + c7*w1[0].w;
      hv.y = bb.y + c0*w0[1].x + c1*w0[1].y + c2*w0[1].z + c3*w0[1].w
                  + c4*w1[1].x + c5*w1[1].y + c6*w1[1].z + c7*w1[1].w;
      hv.z = bb.z + c0*w0[2].x + c1*w0[2].y + c2*w0[2].z + c3*w0[2].w
                  + c4*w1[2].x + c5*w1[2].y + c6*w1[2].z + c7*w1[2].w;
      hv.w = bb.w + c0*w0[3].x + c1*w0[3].y + c2*w0[3].z + c3*w0[3].w
                  + c4*w1[3].x + c5*w1[3].y + c6*w1[3].z + c7*w1[3].w;
      ushort4 hu;
      hu.x = f2bf(fmaxf(hv.x, 0.f)); hu.y = f2bf(fmaxf(hv.y, 0.f));
      hu.z = f2bf(fmaxf(hv.z, 0.f)); hu.w = f2bf(fmaxf(hv.w, 0.f));
      *(ushort4*)&g_h1h[(size_t)(tok0 + tt2)*2048 + j0] = hu;
    }
  }
}

// ---------------- bf16 MFMA GEMM: C[M,N] = A[M,K] @ B[N,K]^T ----------------
// 128x128 tile, BK=32, 4 waves (2x2), global_load_lds staging, XOR-swizzled LDS.
template<int DO_RELU, int DO_ROWSCALE, int OUT_BF16, int HAS_BIAS>
__global__ __launch_bounds__(256) void k_mm(
    const u16* __restrict__ A, const u16* __restrict__ Bm, void* __restrict__ Cv,
    int M, int N, int K,
    const float* __restrict__ rowscale, const float* __restrict__ bias)
{
  __shared__ u16 Asl[128*32];
  __shared__ u16 Bsl[128*32];
  const int t = threadIdx.x;
  const int w = t >> 6, lane = t & 63;
  const int bm = blockIdx.y * 128, bn = blockIdx.x * 128;
  const int wr = w >> 1, wc = w & 1;
  const int lrow = lane >> 2;       // row within 16-row chunk
  const int lslot = lane & 3;       // 16-byte slot
  f32x4 acc[4][4] = {};
  const int fr = lane & 15;
  const int gk = lane >> 4;         // k-group 0..3
  for (int k0 = 0; k0 < K; k0 += 32) {
    const u16* ga = A  + (size_t)(bm + w*32)*K + k0;
    const u16* gb = Bm + (size_t)(bn + w*32)*K + k0;
    u16* la = Asl + w*32*32;
    u16* lb = Bsl + w*32*32;
    #pragma unroll
    for (int c = 0; c < 2; c++) {
      int r = c*16 + lrow;
      int ksw = (lslot ^ (r & 3)) * 8;   // pre-swizzled global k-group
      gl_lds16(ga + (size_t)r*K + ksw, la + c*16*32);
      gl_lds16(gb + (size_t)r*K + ksw, lb + c*16*32);
    }
    __syncthreads();
    bf16x8 af[4], bfv[4];
    #pragma unroll
    for (int rb = 0; rb < 4; rb++) {
      int row = wr*64 + rb*16 + fr;
      af[rb] = *(const bf16x8*)&Asl[row*32 + ((gk ^ (row & 3)) * 8)];
    }
    #pragma unroll
    for (int nb = 0; nb < 4; nb++) {
      int col = wc*64 + nb*16 + fr;
      bfv[nb] = *(const bf16x8*)&Bsl[col*32 + ((gk ^ (col & 3)) * 8)];
    }
    #pragma unroll
    for (int rb = 0; rb < 4; rb++)
      #pragma unroll
      for (int nb = 0; nb < 4; nb++)
        acc[rb][nb] = __builtin_amdgcn_mfma_f32_16x16x32_bf16(af[rb], bfv[nb], acc[rb][nb], 0, 0, 0);
    __syncthreads();
  }
  #pragma unroll
  for (int rb = 0; rb < 4; rb++) {
    #pragma unroll
    for (int r = 0; r < 4; r++) {
      int row = bm + wr*64 + rb*16 + gk*4 + r;
      float rs = DO_ROWSCALE ? rowscale[row] : 1.f;
      #pragma unroll
      for (int nb = 0; nb < 4; nb++) {
        int col = bn + wc*64 + nb*16 + fr;
        float v = acc[rb][nb][r];
        if (HAS_BIAS) v += bias[col];
        if (DO_ROWSCALE) v *= rs;
        if (DO_RELU) v = fmaxf(v, 0.f);
        if (OUT_BF16) ((u16*)Cv)[(size_t)row*N + col] = f2bf(v);
        else ((float*)Cv)[(size_t)row*N + col] = v;
      }
    }
  }
}

// ---------------- K6: LN2 + mean + relu -> bf16 ----------------
__global__ __launch_bounds__(256) void k_ln2_mean(const float* __restrict__ g2,
                                                  const float* __restrict__ b2ln) {
  __shared__ float red[4];
  int n = blockIdx.x, t = threadIdx.x;
  float acc = 0.f;
  for (int f = 0; f < 4; f++) {
    int tok = n*4 + f;
    float v = g_x1[tok*256 + t] + g_ff[tok*256 + t];
    float s1 = blk_sum256(v, red);
    float s2 = blk_sum256(v*v, red);
    float mu = s1 * (1.f/256.f);
    float var = s2 * (1.f/256.f) - mu*mu;
    float x2 = (v - mu) * rsqrtf(var + 1e-5f) * g2[t] + b2ln[t];
    acc += x2;
  }
  g_xmh[n*256 + t] = f2bf(fmaxf(acc * 0.25f, 0.f));
}

// ---------------- GCN graph prep ----------------
__global__ __launch_bounds__(256) void k_zero() {
  int i = blockIdx.x * 256 + threadIdx.x;
  if (i < NN) { g_deg[i] = 0; g_cur[i] = 0; }
}
__global__ __launch_bounds__(256) void k_deg(const int* __restrict__ edges) {
  int e = blockIdx.x * 256 + threadIdx.x;
  if (e >= EE) return;
  atomicAdd(&g_deg[edges[EE + e]], 1);
}
__global__ __launch_bounds__(256) void k_scan() {
  int t = threadIdx.x;
  int base = t * 8;
  int v[8], ex[8], sum = 0;
  #pragma unroll
  for (int i = 0; i < 8; i++) { ex[i] = sum; v[i] = g_deg[base+i]; sum += v[i]; }
  int lane = t & 63, w = t >> 6;
  int inc = sum;
  #pragma unroll
  for (int o = 1; o < 64; o <<= 1) { int x = __shfl_up(inc, o, 64); if (lane >= o) inc += x; }
  __shared__ int wt[4];
  if (lane == 63) wt[w] = inc;
  __syncthreads();
  int wb = 0;
  for (int j = 0; j < w; j++) wb += wt[j];
  int excl = wb + inc - sum;
  #pragma unroll
  for (int i = 0; i < 8; i++) {
    g_off[base+i] = excl + ex[i];
    g_dinv[base+i] = rsqrtf((float)(v[i] + 1));
  }
  if (t == 255) g_off[NN] = wb + inc;
}
__global__ __launch_bounds__(256) void k_fill(const int* __restrict__ edges) {
  int e = blockIdx.x * 256 + threadIdx.x;
  if (e >= EE) return;
  int s = edges[e], d = edges[EE + e];
  int pos = atomicAdd(&g_cur[d], 1);
  g_adj[g_off[d] + pos] = s;
}

// ---------------- GCN aggregation (bf16 gather, fp32 accum) ----------------
template<int OUT_BF16, int DO_RELU>
__global__ __launch_bounds__(128) void k_agg(const float* __restrict__ bias,
                                             void* __restrict__ outv) {
  int i = blockIdx.x, t = threadIdx.x;
  int d = t * 4;
  ushort4 sv = *(const ushort4*)&g_hsh[i*512 + d];
  float a0 = bf2f(sv.x), a1 = bf2f(sv.y), a2 = bf2f(sv.z), a3 = bf2f(sv.w);
  int e0 = g_off[i], e1 = g_off[i+1];
  for (int e = e0; e < e1; e++) {
    int s = g_adj[e];
    ushort4 v = *(const ushort4*)&g_hsh[s*512 + d];
    a0 += bf2f(v.x); a1 += bf2f(v.y); a2 += bf2f(v.z); a3 += bf2f(v.w);
  }
  float di = g_dinv[i];
  const float4 bb = *(const float4*)&bias[d];
  a0 = di*a0 + bb.x; a1 = di*a1 + bb.y; a2 = di*a2 + bb.z; a3 = di*a3 + bb.w;
  if (DO_RELU) { a0=fmaxf(a0,0.f); a1=fmaxf(a1,0.f); a2=fmaxf(a2,0.f); a3=fmaxf(a3,0.f); }
  if (OUT_BF16) {
    ushort4 r; r.x=f2bf(a0); r.y=f2bf(a1); r.z=f2bf(a2); r.w=f2bf(a3);
    *(ushort4*)&((u16*)outv)[i*512 + d] = r;
  } else {
    float4 r; r.x=a0; r.y=a1; r.z=a2; r.w=a3;
    *(float4*)&((float*)outv)[i*512 + d] = r;
  }
}

// ---------------- host ----------------
static float* symf(const void* s) { void* p = nullptr; (void)hipGetSymbolAddress(&p, s); return (float*)p; }

extern "C" void kernel_launch(void* const* d_in, const int* in_sizes, int n_in,
                              void* d_out, int out_size, void* d_ws, size_t ws_size,
                              hipStream_t stream) {
  const float* feat = (const float*)d_in[0];
  const int*   edges= (const int*)  d_in[1];
  const float* linw = (const float*)d_in[2];
  const float* linb = (const float*)d_in[3];
  const float* ipw  = (const float*)d_in[4];
  const float* ipb  = (const float*)d_in[5];
  const float* outw = (const float*)d_in[6];
  const float* outb = (const float*)d_in[7];
  const float* ln1g = (const float*)d_in[8];
  const float* ln1b = (const float*)d_in[9];
  const float* fw1  = (const float*)d_in[10];
  const float* fb1  = (const float*)d_in[11];
  const float* fw2  = (const float*)d_in[12];
  const float* fb2  = (const float*)d_in[13];
  const float* ln2g = (const float*)d_in[14];
  const float* ln2b = (const float*)d_in[15];
  const float* W1g  = (const float*)d_in[16];
  const float* b1g  = (const float*)d_in[17];
  const float* W2g  = (const float*)d_in[18];
  const float* b2g  = (const float*)d_in[19];
  const float* W3g  = (const float*)d_in[20];
  const float* b3g  = (const float*)d_in[21];
  const float* W4g  = (const float*)d_in[22];
  const float* b4g  = (const float*)d_in[23];
  float* out = (float*)d_out;

  u16*   p_h1h = (u16*)symf(HIP_SYMBOL(g_h1h));
  float* p_ff  = symf(HIP_SYMBOL(g_ff));
  u16*   p_xmh = (u16*)symf(HIP_SYMBOL(g_xmh));
  u16*   p_hsh = (u16*)symf(HIP_SYMBOL(g_hsh));
  u16*   p_xgh = (u16*)symf(HIP_SYMBOL(g_xgh));
  u16*   p_w2h = (u16*)symf(HIP_SYMBOL(g_w2h));
  u16*   p_wgh = (u16*)symf(HIP_SYMBOL(g_wgh));
  float* p_dinv= symf(HIP_SYMBOL(g_dinv));

  // transformer prep (rank-1 collapse)
  k_prep_ab  <<<3, 256, 0, stream>>>(ipw, ipb, linw, linb);
  k_prep_head<<<1, 256, 0, stream>>>(outw, outb, linw, linb, ln1g, ln1b);
  k_w1v      <<<8, 256, 0, stream>>>(fw1);
  // weight conversions to bf16
  k_cvt<<<512, 256, 0, stream>>>(fw2, p_w2h, 256*2048);
  k_cvt<<<128, 256, 0, stream>>>(W1g, p_wgh, 512*256);
  k_cvt<<<256, 256, 0, stream>>>(W2g, p_wgh + 131072, 512*512);
  k_cvt<<<256, 256, 0, stream>>>(W3g, p_wgh + 393216, 512*512);
  k_cvt<<<256, 256, 0, stream>>>(W4g, p_wgh + 655360, 512*512);

  k_attn_m<<<512, 256, 0, stream>>>(feat);
  k_token <<<512, 256, 0, stream>>>(feat, fb1);
  // FFN2: ff = h1 @ W2^T + b2   (bf16 MFMA, fp32 out)
  k_mm<0,0,0,1><<<dim3(256/128, NT/128), 256, 0, stream>>>(
      p_h1h, p_w2h, p_ff, NT, 256, 2048, nullptr, fb2);
  k_ln2_mean<<<NN, 256, 0, stream>>>(ln2g, ln2b);

  // graph prep
  k_zero<<<8, 256, 0, stream>>>();
  k_deg <<<EE/256, 256, 0, stream>>>(edges);
  k_scan<<<1, 256, 0, stream>>>();
  k_fill<<<EE/256, 256, 0, stream>>>(edges);

  // GCN layers: hs = dinv ∘ (x @ W^T) [bf16 MFMA]; agg = dinv*(self+nbrs)+b
  k_mm<0,1,1,0><<<dim3(4, 16), 256, 0, stream>>>(
      p_xmh, p_wgh, p_hsh, NN, 512, 256, p_dinv, nullptr);
  k_agg<1,1><<<NN, 128, 0, stream>>>(b1g, p_xgh);
  k_mm<0,1,1,0><<<dim3(4, 16), 256, 0, stream>>>(
      p_xgh, p_wgh + 131072, p_hsh, NN, 512, 512, p_dinv, nullptr);
  k_agg<1,1><<<NN, 128, 0, stream>>>(b2g, p_xgh);
  k_mm<0,1,1,0><<<dim3(4, 16), 256, 0, stream>>>(
      p_xgh, p_wgh + 393216, p_hsh, NN, 512, 512, p_dinv, nullptr);
  k_agg<1,1><<<NN, 128, 0, stream>>>(b3g, p_xgh);
  k_mm<0,1,1,0><<<dim3(4, 16), 256, 0, stream>>>(
      p_xgh, p_wgh + 655360, p_hsh, NN, 512, 512, p_dinv, nullptr);
  k_agg<0,0><<<NN, 128, 0, stream>>>(b4g, out);
}

// Round 4
// 268.452 us; speedup vs baseline: 1.5973x; 1.1645x over previous
//
#include <hip/hip_runtime.h>
#include <hip/hip_bf16.h>
#include <math.h>

// Problem constants
#define NN   2048
#define FB   4
#define DD   256
#define EE   65536
#define NT   (NN*FB)
#define FFD  2048

typedef unsigned int u32;
typedef unsigned short u16;
typedef __attribute__((ext_vector_type(4))) float f32x4;
typedef __attribute__((ext_vector_type(8))) short bf16x8;

// weight buffer offsets (bf16 elements)
#define OFF_W2   0
#define OFF_G1   524288
#define OFF_G2   655360
#define OFF_G3   917504
#define OFF_G4   1179648
#define WBF_TOT  1441792

// ---------------- static device scratch ----------------
__device__ float g_A[768], g_B[768];
__device__ float g_coefA[4], g_coefC[4];
__device__ float g_meanv[6], g_G[36];
__device__ float g_Vx[8*DD];
__device__ float g_W1V[FFD*8];
__device__ float g_m[NT*4];
__device__ float g_x1[NT*DD];
__device__ u16   g_h1h[(size_t)NT*FFD];     // h1 in bf16 (32 MB)
__device__ float g_ff[NT*DD];
__device__ u16   g_xmh[NN*DD];              // GCN input bf16
__device__ u16   g_hsh[NN*512];             // per-layer transformed (dinv-scaled) bf16
__device__ u16   g_xgh[NN*512];             // per-layer activations bf16
__device__ u16   g_wbf[WBF_TOT];            // all GEMM weights bf16
__device__ int   g_deg[NN], g_off[NN+1], g_cur[NN], g_adj[EE];
__device__ float g_dinv[NN];

// ---------------- helpers ----------------
__device__ __forceinline__ u16 f2bf(float x) {
  u32 u = __float_as_uint(x);
  return (u16)((u + 0x7FFFu + ((u >> 16) & 1u)) >> 16);
}
__device__ __forceinline__ float bf2f(u16 x) {
  return __uint_as_float(((u32)x) << 16);
}
__device__ __forceinline__ void gl_lds16(const void* g, void* l) {
  __builtin_amdgcn_global_load_lds(
      (const __attribute__((address_space(1))) u32*)g,
      (__attribute__((address_space(3))) u32*)l, 16, 0, 0);
}
__device__ __forceinline__ float blk_sum256(float v, float* red) {
  #pragma unroll
  for (int o = 32; o > 0; o >>= 1) v += __shfl_down(v, o, 64);
  int lane = threadIdx.x & 63, w = threadIdx.x >> 6;
  __syncthreads();
  if (lane == 0) red[w] = v;
  __syncthreads();
  return red[0] + red[1] + red[2] + red[3];
}

// ---------------- K1: rank-1 qkv coefficients ----------------
__global__ __launch_bounds__(256) void k_prep_ab(const float* __restrict__ ipw,
    const float* __restrict__ ipb, const float* __restrict__ linw,
    const float* __restrict__ linb) {
  int j = blockIdx.x * 256 + threadIdx.x;
  if (j >= 768) return;
  float a = 0.f, b = 0.f;
  for (int d = 0; d < 256; d++) {
    float w = ipw[j * 256 + d];
    a += w * linw[d];
    b += w * linb[d];
  }
  g_A[j] = a;
  g_B[j] = b + ipb[j];
}

// ---------------- K2: head scalars, Gram, basis Vx ----------------
__global__ __launch_bounds__(256) void k_prep_head(const float* __restrict__ outw,
    const float* __restrict__ outb, const float* __restrict__ linw,
    const float* __restrict__ linb, const float* __restrict__ g1,
    const float* __restrict__ b1ln) {
  __shared__ float red[4];
  int t = threadIdx.x, lane = t & 63, w = t >> 6;
  {
    float aq = g_A[w*64 + lane], ak = g_A[256 + w*64 + lane], bq = g_B[w*64 + lane];
    float pa = aq * ak, pc = bq * ak;
    #pragma unroll
    for (int o = 32; o > 0; o >>= 1) { pa += __shfl_down(pa, o, 64); pc += __shfl_down(pc, o, 64); }
    if (lane == 0) { g_coefA[w] = pa * 0.125f; g_coefC[w] = pc * 0.125f; }
  }
  int d = t;
  float pv[4];
  for (int h = 0; h < 4; h++) {
    float sv = 0.f;
    for (int u = 0; u < 64; u++) sv += outw[d*256 + h*64 + u] * g_A[512 + h*64 + u];
    pv[h] = sv;
  }
  float q0 = 0.f;
  for (int e = 0; e < 256; e++) q0 += outw[d*256 + e] * g_B[512 + e];
  q0 += outb[d];
  float c0 = linb[d] + q0;
  float Mv[6] = { linw[d], pv[0], pv[1], pv[2], pv[3], c0 };
  for (int k = 0; k < 6; k++) {
    float s = blk_sum256(Mv[k], red);
    if (t == 0) g_meanv[k] = s * (1.f/256.f);
  }
  for (int k = 0; k < 6; k++)
    for (int l = k; l < 6; l++) {
      float s = blk_sum256(Mv[k] * Mv[l], red);
      if (t == 0) { g_G[k*6+l] = s; g_G[l*6+k] = s; }
    }
  for (int k = 0; k < 6; k++) g_Vx[k*256 + d] = Mv[k] * g1[d];
  g_Vx[6*256 + d] = g1[d];
  g_Vx[7*256 + d] = b1ln[d];
}

// ---------------- K2c: W1V[j][k] = W1[j,:]·Vx_k ----------------
__global__ __launch_bounds__(256) void k_w1v(const float* __restrict__ w1) {
  __shared__ float vx[8][256];
  int t = threadIdx.x;
  for (int k = 0; k < 8; k++) vx[k][t] = g_Vx[k*256 + t];
  __syncthreads();
  int j = blockIdx.x * 256 + t;
  float acc[8] = {0,0,0,0,0,0,0,0};
  for (int d = 0; d < 256; d++) {
    float w = w1[j*256 + d];
    #pragma unroll
    for (int k = 0; k < 8; k++) acc[k] += w * vx[k][d];
  }
  #pragma unroll
  for (int k = 0; k < 8; k++) g_W1V[j*8 + k] = acc[k];
}

// ---------------- fused cvt fp32 -> bf16 of all GEMM weights ----------------
__global__ __launch_bounds__(256) void k_cvt_all(const float* __restrict__ w2,
    const float* __restrict__ W1, const float* __restrict__ W2,
    const float* __restrict__ W3, const float* __restrict__ W4) {
  int i = (blockIdx.x * 256 + threadIdx.x) * 4;
  const float* src; int off;
  if (i < OFF_G1)      { src = w2; off = OFF_W2; }
  else if (i < OFF_G2) { src = W1; off = OFF_G1; }
  else if (i < OFF_G3) { src = W2; off = OFF_G2; }
  else if (i < OFF_G4) { src = W3; off = OFF_G3; }
  else                 { src = W4; off = OFF_G4; }
  float4 v = *(const float4*)&src[i - off];
  ushort4 r;
  r.x = f2bf(v.x); r.y = f2bf(v.y); r.z = f2bf(v.z); r.w = f2bf(v.w);
  *(ushort4*)&g_wbf[i] = r;
}

// ---------------- K3: softmax-weighted feature means ----------------
__global__ __launch_bounds__(256) void k_attn_m(const float* __restrict__ feat) {
  __shared__ float fs[4][2048];
  __shared__ float ss[64][4], ww[64][4];
  int t = threadIdx.x;
  for (int i = t; i < 2048; i += 256) {
    const float4 v = *(const float4*)&feat[i*4];
    fs[0][i] = v.x; fs[1][i] = v.y; fs[2][i] = v.z; fs[3][i] = v.w;
  }
  __syncthreads();
  int tuple = blockIdx.x * 64 + (t >> 2);
  int c = t & 3;
  int h = tuple & 3, f = (tuple >> 2) & 3, n = tuple >> 4;
  float fi = fs[f][n];
  float tt = g_coefA[h] * fi + g_coefC[h];
  float s = 0.f, wsum = 0.f;
  int j0 = c * 512;
  for (int j = j0; j < j0 + 512; j++) {
    float fj = fs[f][j];
    float e = __expf(tt * fj);
    s += e; wsum += e * fj;
  }
  ss[t>>2][c] = s; ww[t>>2][c] = wsum;
  __syncthreads();
  if (c == 0) {
    float S = ss[t>>2][0] + ss[t>>2][1] + ss[t>>2][2] + ss[t>>2][3];
    float W = ww[t>>2][0] + ww[t>>2][1] + ww[t>>2][2] + ww[t>>2][3];
    g_m[tuple] = W / S;
  }
}

// ---------------- K4: per-token LN1 coeffs -> x1 (f32), h1 (bf16) ----------------
__global__ __launch_bounds__(256) void k_token(const float* __restrict__ feat,
                                               const float* __restrict__ fb1) {
  __shared__ float vx[8][256];
  __shared__ float cc[16][8];
  int t = threadIdx.x;
  for (int k = 0; k < 8; k++) vx[k][t] = g_Vx[k*256 + t];
  if (t < 16) {
    int tok = blockIdx.x * 16 + t;
    int n = tok >> 2, f = tok & 3;
    float fi = feat[n*4 + f];
    float u[6] = { fi, g_m[tok*4+0], g_m[tok*4+1], g_m[tok*4+2], g_m[tok*4+3], 1.f };
    float mu = 0.f;
    #pragma unroll
    for (int k = 0; k < 6; k++) mu += g_meanv[k] * u[k];
    float q = 0.f;
    for (int k = 0; k < 6; k++)
      for (int l = 0; l < 6; l++) q += u[k] * g_G[k*6+l] * u[l];
    q *= (1.f/256.f);
    float var = q - mu * mu;
    float s = rsqrtf(var + 1e-5f);
    cc[t][0] = fi * s; cc[t][1] = u[1]*s; cc[t][2] = u[2]*s; cc[t][3] = u[3]*s;
    cc[t][4] = u[4]*s; cc[t][5] = s; cc[t][6] = -mu*s; cc[t][7] = 1.f;
  }
  __syncthreads();
  int tok0 = blockIdx.x * 16;
  for (int tt2 = 0; tt2 < 16; tt2++) {
    float v = 0.f;
    #pragma unroll
    for (int k = 0; k < 8; k++) v += cc[tt2][k] * vx[k][t];
    g_x1[(tok0 + tt2)*256 + t] = v;
  }
  for (int jj = 0; jj < 2; jj++) {
    int j0 = jj * 1024 + t * 4;
    float4 w0[4], w1[4];
    #pragma unroll
    for (int qj = 0; qj < 4; qj++) {
      w0[qj] = *(const float4*)&g_W1V[(j0+qj)*8];
      w1[qj] = *(const float4*)&g_W1V[(j0+qj)*8 + 4];
    }
    const float4 bb = *(const float4*)&fb1[j0];
    for (int tt2 = 0; tt2 < 16; tt2++) {
      float c0=cc[tt2][0], c1=cc[tt2][1], c2=cc[tt2][2], c3=cc[tt2][3];
      float c4=cc[tt2][4], c5=cc[tt2][5], c6=cc[tt2][6], c7=cc[tt2][7];
      float4 hv;
      hv.x = bb.x + c0*w0[0].x + c1*w0[0].y + c2*w0[0].z + c3*w0[0].w
                  + c4*w1[0].x + c5*w1[0].y + c6*w1[0].z + c7*w1[0].w;
      hv.y = bb.y + c0*w0[1].x + c1*w0[1].y + c2*w0[1].z + c3*w0[1].w
                  + c4*w1[1].x + c5*w1[1].y + c6*w1[1].z + c7*w1[1].w;
      hv.z = bb.z + c0*w0[2].x + c1*w0[2].y + c2*w0[2].z + c3*w0[2].w
                  + c4*w1[2].x + c5*w1[2].y + c6*w1[2].z + c7*w1[2].w;
      hv.w = bb.w + c0*w0[3].x + c1*w0[3].y + c2*w0[3].z + c3*w0[3].w
                  + c4*w1[3].x + c5*w1[3].y + c6*w1[3].z + c7*w1[3].w;
      ushort4 hu;
      hu.x = f2bf(fmaxf(hv.x, 0.f)); hu.y = f2bf(fmaxf(hv.y, 0.f));
      hu.z = f2bf(fmaxf(hv.z, 0.f)); hu.w = f2bf(fmaxf(hv.w, 0.f));
      *(ushort4*)&g_h1h[(size_t)(tok0 + tt2)*2048 + j0] = hu;
    }
  }
}

// ---------------- bf16 MFMA GEMM: C[M,N] = A[M,K] @ B[N,K]^T ----------------
// 64x64 tile, BK=64, 4 waves (2x2) each 32x32 via 2x2 16x16x32 frags.
// XOR swizzle over 8x16B slots per 128B row -> ~2-way LDS conflicts.
template<int DO_ROWSCALE, int OUT_BF16, int HAS_BIAS>
__global__ __launch_bounds__(256) void k_mm64(
    const u16* __restrict__ A, const u16* __restrict__ Bm, void* __restrict__ Cv,
    int M, int N, int K,
    const float* __restrict__ rowscale, const float* __restrict__ bias)
{
  __shared__ u16 Asl[64*64];
  __shared__ u16 Bsl[64*64];
  const int t = threadIdx.x;
  const int w = t >> 6, lane = t & 63;
  const int bm = blockIdx.y * 64, bn = blockIdx.x * 64;
  const int wr = w >> 1, wc = w & 1;
  const int fr = lane & 15;
  const int gk = lane >> 4;            // 0..3
  const int sslot = lane & 7;          // staging 16B slot within row
  f32x4 acc[2][2] = {};
  for (int k0 = 0; k0 < K; k0 += 64) {
    // stage 64x64 A and B tiles: wave w covers rows 16w..16w+16, 2 chunks of 8 rows
    #pragma unroll
    for (int c = 0; c < 2; c++) {
      int r = (w << 4) + (c << 3) + (lane >> 3);
      int ks = ((sslot ^ (r & 7)) << 3);           // swizzled k-offset (elements)
      gl_lds16(A  + (size_t)(bm + r)*K + k0 + ks, Asl + (w << 10) + (c << 9));
      gl_lds16(Bm + (size_t)(bn + r)*K + k0 + ks, Bsl + (w << 10) + (c << 9));
    }
    __syncthreads();
    bf16x8 af[2][2], bfv[2][2];                    // [frag][ksub]
    #pragma unroll
    for (int rb = 0; rb < 2; rb++) {
      int row = wr*32 + rb*16 + fr;
      #pragma unroll
      for (int kk = 0; kk < 2; kk++) {
        int q = (kk << 2) + gk;
        af[rb][kk] = *(const bf16x8*)&Asl[(row << 6) + ((q ^ (row & 7)) << 3)];
      }
    }
    #pragma unroll
    for (int nb = 0; nb < 2; nb++) {
      int col = wc*32 + nb*16 + fr;
      #pragma unroll
      for (int kk = 0; kk < 2; kk++) {
        int q = (kk << 2) + gk;
        bfv[nb][kk] = *(const bf16x8*)&Bsl[(col << 6) + ((q ^ (col & 7)) << 3)];
      }
    }
    #pragma unroll
    for (int kk = 0; kk < 2; kk++)
      #pragma unroll
      for (int rb = 0; rb < 2; rb++)
        #pragma unroll
        for (int nb = 0; nb < 2; nb++)
          acc[rb][nb] = __builtin_amdgcn_mfma_f32_16x16x32_bf16(af[rb][kk], bfv[nb][kk], acc[rb][nb], 0, 0, 0);
    __syncthreads();
  }
  #pragma unroll
  for (int rb = 0; rb < 2; rb++) {
    #pragma unroll
    for (int r = 0; r < 4; r++) {
      int row = bm + wr*32 + rb*16 + gk*4 + r;
      float rs = DO_ROWSCALE ? rowscale[row] : 1.f;
      #pragma unroll
      for (int nb = 0; nb < 2; nb++) {
        int col = bn + wc*32 + nb*16 + fr;
        float v = acc[rb][nb][r];
        if (HAS_BIAS) v += bias[col];
        if (DO_ROWSCALE) v *= rs;
        if (OUT_BF16) ((u16*)Cv)[(size_t)row*N + col] = f2bf(v);
        else ((float*)Cv)[(size_t)row*N + col] = v;
      }
    }
  }
}

// ---------------- K6: LN2 + mean + relu -> bf16 ----------------
__global__ __launch_bounds__(256) void k_ln2_mean(const float* __restrict__ g2,
                                                  const float* __restrict__ b2ln) {
  __shared__ float red[4];
  int n = blockIdx.x, t = threadIdx.x;
  float acc = 0.f;
  for (int f = 0; f < 4; f++) {
    int tok = n*4 + f;
    float v = g_x1[tok*256 + t] + g_ff[tok*256 + t];
    float s1 = blk_sum256(v, red);
    float s2 = blk_sum256(v*v, red);
    float mu = s1 * (1.f/256.f);
    float var = s2 * (1.f/256.f) - mu*mu;
    float x2 = (v - mu) * rsqrtf(var + 1e-5f) * g2[t] + b2ln[t];
    acc += x2;
  }
  g_xmh[n*256 + t] = f2bf(fmaxf(acc * 0.25f, 0.f));
}

// ---------------- GCN graph prep ----------------
__global__ __launch_bounds__(256) void k_zero() {
  int i = blockIdx.x * 256 + threadIdx.x;
  if (i < NN) { g_deg[i] = 0; g_cur[i] = 0; }
}
__global__ __launch_bounds__(256) void k_deg(const int* __restrict__ edges) {
  int e = blockIdx.x * 256 + threadIdx.x;
  if (e >= EE) return;
  atomicAdd(&g_deg[edges[EE + e]], 1);
}
__global__ __launch_bounds__(256) void k_scan() {
  int t = threadIdx.x;
  int base = t * 8;
  int v[8], ex[8], sum = 0;
  #pragma unroll
  for (int i = 0; i < 8; i++) { ex[i] = sum; v[i] = g_deg[base+i]; sum += v[i]; }
  int lane = t & 63, w = t >> 6;
  int inc = sum;
  #pragma unroll
  for (int o = 1; o < 64; o <<= 1) { int x = __shfl_up(inc, o, 64); if (lane >= o) inc += x; }
  __shared__ int wt[4];
  if (lane == 63) wt[w] = inc;
  __syncthreads();
  int wb = 0;
  for (int j = 0; j < w; j++) wb += wt[j];
  int excl = wb + inc - sum;
  #pragma unroll
  for (int i = 0; i < 8; i++) {
    g_off[base+i] = excl + ex[i];
    g_dinv[base+i] = rsqrtf((float)(v[i] + 1));
  }
  if (t == 255) g_off[NN] = wb + inc;
}
__global__ __launch_bounds__(256) void k_fill(const int* __restrict__ edges) {
  int e = blockIdx.x * 256 + threadIdx.x;
  if (e >= EE) return;
  int s = edges[e], d = edges[EE + e];
  int pos = atomicAdd(&g_cur[d], 1);
  g_adj[g_off[d] + pos] = s;
}

// ---------------- GCN aggregation (bf16 gather, fp32 accum) ----------------
template<int OUT_BF16, int DO_RELU>
__global__ __launch_bounds__(128) void k_agg(const float* __restrict__ bias,
                                             void* __restrict__ outv) {
  int i = blockIdx.x, t = threadIdx.x;
  int d = t * 4;
  ushort4 sv = *(const ushort4*)&g_hsh[i*512 + d];
  float a0 = bf2f(sv.x), a1 = bf2f(sv.y), a2 = bf2f(sv.z), a3 = bf2f(sv.w);
  int e0 = g_off[i], e1 = g_off[i+1];
  for (int e = e0; e < e1; e++) {
    int s = g_adj[e];
    ushort4 v = *(const ushort4*)&g_hsh[s*512 + d];
    a0 += bf2f(v.x); a1 += bf2f(v.y); a2 += bf2f(v.z); a3 += bf2f(v.w);
  }
  float di = g_dinv[i];
  const float4 bb = *(const float4*)&bias[d];
  a0 = di*a0 + bb.x; a1 = di*a1 + bb.y; a2 = di*a2 + bb.z; a3 = di*a3 + bb.w;
  if (DO_RELU) { a0=fmaxf(a0,0.f); a1=fmaxf(a1,0.f); a2=fmaxf(a2,0.f); a3=fmaxf(a3,0.f); }
  if (OUT_BF16) {
    ushort4 r; r.x=f2bf(a0); r.y=f2bf(a1); r.z=f2bf(a2); r.w=f2bf(a3);
    *(ushort4*)&((u16*)outv)[i*512 + d] = r;
  } else {
    float4 r; r.x=a0; r.y=a1; r.z=a2; r.w=a3;
    *(float4*)&((float*)outv)[i*512 + d] = r;
  }
}

// ---------------- host ----------------
static float* symf(const void* s) { void* p = nullptr; (void)hipGetSymbolAddress(&p, s); return (float*)p; }

extern "C" void kernel_launch(void* const* d_in, const int* in_sizes, int n_in,
                              void* d_out, int out_size, void* d_ws, size_t ws_size,
                              hipStream_t stream) {
  const float* feat = (const float*)d_in[0];
  const int*   edges= (const int*)  d_in[1];
  const float* linw = (const float*)d_in[2];
  const float* linb = (const float*)d_in[3];
  const float* ipw  = (const float*)d_in[4];
  const float* ipb  = (const float*)d_in[5];
  const float* outw = (const float*)d_in[6];
  const float* outb = (const float*)d_in[7];
  const float* ln1g = (const float*)d_in[8];
  const float* ln1b = (const float*)d_in[9];
  const float* fw1  = (const float*)d_in[10];
  const float* fb1  = (const float*)d_in[11];
  const float* fw2  = (const float*)d_in[12];
  const float* fb2  = (const float*)d_in[13];
  const float* ln2g = (const float*)d_in[14];
  const float* ln2b = (const float*)d_in[15];
  const float* W1g  = (const float*)d_in[16];
  const float* b1g  = (const float*)d_in[17];
  const float* W2g  = (const float*)d_in[18];
  const float* b2g  = (const float*)d_in[19];
  const float* W3g  = (const float*)d_in[20];
  const float* b3g  = (const float*)d_in[21];
  const float* W4g  = (const float*)d_in[22];
  const float* b4g  = (const float*)d_in[23];
  float* out = (float*)d_out;

  u16*   p_h1h = (u16*)symf(HIP_SYMBOL(g_h1h));
  float* p_ff  = symf(HIP_SYMBOL(g_ff));
  u16*   p_xmh = (u16*)symf(HIP_SYMBOL(g_xmh));
  u16*   p_hsh = (u16*)symf(HIP_SYMBOL(g_hsh));
  u16*   p_xgh = (u16*)symf(HIP_SYMBOL(g_xgh));
  u16*   p_wbf = (u16*)symf(HIP_SYMBOL(g_wbf));
  float* p_dinv= symf(HIP_SYMBOL(g_dinv));

  // graph prep early (independent of transformer)
  k_zero<<<8, 256, 0, stream>>>();
  k_deg <<<EE/256, 256, 0, stream>>>(edges);
  k_scan<<<1, 256, 0, stream>>>();
  k_fill<<<EE/256, 256, 0, stream>>>(edges);

  // transformer prep (rank-1 collapse)
  k_prep_ab  <<<3, 256, 0, stream>>>(ipw, ipb, linw, linb);
  k_prep_head<<<1, 256, 0, stream>>>(outw, outb, linw, linb, ln1g, ln1b);
  k_w1v      <<<8, 256, 0, stream>>>(fw1);
  k_cvt_all  <<<WBF_TOT/1024, 256, 0, stream>>>(fw2, W1g, W2g, W3g, W4g);

  k_attn_m<<<512, 256, 0, stream>>>(feat);
  k_token <<<512, 256, 0, stream>>>(feat, fb1);
  // FFN2: ff = h1 @ W2^T + b2   (bf16 MFMA, fp32 out)
  k_mm64<0,0,1><<<dim3(256/64, NT/64), 256, 0, stream>>>(
      p_h1h, p_wbf + OFF_W2, p_ff, NT, 256, 2048, nullptr, fb2);
  k_ln2_mean<<<NN, 256, 0, stream>>>(ln2g, ln2b);

  // GCN layers: hs = dinv ∘ (x @ W^T) [bf16 MFMA]; agg = dinv*(self+nbrs)+b
  k_mm64<1,1,0><<<dim3(8, 32), 256, 0, stream>>>(
      p_xmh, p_wbf + OFF_G1, p_hsh, NN, 512, 256, p_dinv, nullptr);
  k_agg<1,1><<<NN, 128, 0, stream>>>(b1g, p_xgh);
  k_mm64<1,1,0><<<dim3(8, 32), 256, 0, stream>>>(
      p_xgh, p_wbf + OFF_G2, p_hsh, NN, 512, 512, p_dinv, nullptr);
  k_agg<1,1><<<NN, 128, 0, stream>>>(b2g, p_xgh);
  k_mm64<1,1,0><<<dim3(8, 32), 256, 0, stream>>>(
      p_xgh, p_wbf + OFF_G3, p_hsh, NN, 512, 512, p_dinv, nullptr);
  k_agg<1,1><<<NN, 128, 0, stream>>>(b3g, p_xgh);
  k_mm64<1,1,0><<<dim3(8, 32), 256, 0, stream>>>(
      p_xgh, p_wbf + OFF_G4, p_hsh, NN, 512, 512, p_dinv, nullptr);
  k_agg<0,0><<<NN, 128, 0, stream>>>(b4g, out);
}

// Round 5
// 211.037 us; speedup vs baseline: 2.0319x; 1.2721x over previous
//
#include <hip/hip_runtime.h>
#include <hip/hip_bf16.h>
#include <math.h>

// Problem constants
#define NN   2048
#define FB   4
#define DD   256
#define EE   65536
#define NT   (NN*FB)
#define FFD  2048

typedef unsigned int u32;
typedef unsigned short u16;
typedef __attribute__((ext_vector_type(4))) float f32x4;
typedef __attribute__((ext_vector_type(8))) short bf16x8;

// weight buffer offsets (bf16 elements)
#define OFF_W2   0
#define OFF_G1   524288
#define OFF_G2   655360
#define OFF_G3   917504
#define OFF_G4   1179648
#define WBF_TOT  1441792

// ---------------- static device scratch ----------------
__device__ float g_A[768], g_B[768];
__device__ float g_coefA[4], g_coefC[4];
__device__ float g_meanv[6], g_G[36];
__device__ float g_Vx[8*DD];
__device__ float g_W1V[FFD*8];
__device__ float g_m[NT*4];
__device__ float g_cc[NT*8];                // per-token LN1 coefficients
__device__ u16   g_h1h[(size_t)NT*FFD];     // h1 in bf16 (32 MB)
__device__ float g_ff[NT*DD];
__device__ u16   g_xmh[NN*DD];              // GCN input bf16
__device__ u16   g_hsh[NN*512];             // per-layer transformed bf16 (2 MB, L2-resident)
__device__ u16   g_xgh[NN*512];             // per-layer activations bf16
__device__ u16   g_wbf[WBF_TOT];            // all GEMM weights bf16
__device__ int   g_deg[NN], g_off[NN+1], g_cur[NN], g_adj[EE];
__device__ float g_dinv[NN];

// ---------------- helpers ----------------
__device__ __forceinline__ u16 f2bf(float x) {
  u32 u = __float_as_uint(x);
  return (u16)((u + 0x7FFFu + ((u >> 16) & 1u)) >> 16);
}
__device__ __forceinline__ float bf2f(u16 x) {
  return __uint_as_float(((u32)x) << 16);
}
__device__ __forceinline__ void gl_lds16(const void* g, void* l) {
  __builtin_amdgcn_global_load_lds(
      (const __attribute__((address_space(1))) u32*)g,
      (__attribute__((address_space(3))) u32*)l, 16, 0, 0);
}
__device__ __forceinline__ float qred(float v) {   // reduce across 4-lane quad
  v += __shfl_xor(v, 1, 64);
  v += __shfl_xor(v, 2, 64);
  return v;
}
__device__ __forceinline__ void acc8(const uint4 v, float* a) {
  a[0]+=__uint_as_float(v.x<<16); a[1]+=__uint_as_float(v.x&0xffff0000u);
  a[2]+=__uint_as_float(v.y<<16); a[3]+=__uint_as_float(v.y&0xffff0000u);
  a[4]+=__uint_as_float(v.z<<16); a[5]+=__uint_as_float(v.z&0xffff0000u);
  a[6]+=__uint_as_float(v.w<<16); a[7]+=__uint_as_float(v.w&0xffff0000u);
}

// ================= FUSE-1: prep_ab (blk 0..11)  ||  zero (blk 12..19) =================
__global__ __launch_bounds__(256) void k_fuse1(const float* __restrict__ ipw,
    const float* __restrict__ ipb, const float* __restrict__ linw,
    const float* __restrict__ linb) {
  __shared__ __align__(16) float sm[512];
  const int b = blockIdx.x, t = threadIdx.x;
  if (b < 12) {
    float* lw = sm; float* lb = sm + 256;
    lw[t] = linw[t]; lb[t] = linb[t];
    __syncthreads();
    int j = b*64 + (t>>2), c = t&3;
    const float4* row = (const float4*)&ipw[j*256 + c*64];
    float a = 0.f, bb = 0.f;
    #pragma unroll
    for (int q = 0; q < 16; q++) {
      float4 v = row[q]; int d0 = c*64 + q*4;
      a  += v.x*lw[d0] + v.y*lw[d0+1] + v.z*lw[d0+2] + v.w*lw[d0+3];
      bb += v.x*lb[d0] + v.y*lb[d0+1] + v.z*lb[d0+2] + v.w*lb[d0+3];
    }
    a = qred(a); bb = qred(bb);
    if (c == 0) { g_A[j] = a; g_B[j] = bb + ipb[j]; }
  } else {
    int i = (b - 12)*256 + t;
    if (i < NN) { g_deg[i] = 0; g_cur[i] = 0; }
  }
}

// ================= FUSE-2: prep_head (blk 0)  ||  deg (blk 1..256) =================
__global__ __launch_bounds__(256) void k_fuse2(const float* __restrict__ outw,
    const float* __restrict__ outb, const float* __restrict__ linw,
    const float* __restrict__ linb, const float* __restrict__ g1,
    const float* __restrict__ b1ln, const int* __restrict__ edges) {
  __shared__ __align__(16) float sm[512 + 4*27];
  const int b = blockIdx.x, t = threadIdx.x;
  if (b == 0) {
    int lane = t & 63, w = t >> 6;
    // per-head softmax scalars
    {
      float aq = g_A[w*64 + lane], ak = g_A[256 + w*64 + lane], bq = g_B[w*64 + lane];
      float pa = aq * ak, pc = bq * ak;
      #pragma unroll
      for (int o = 32; o > 0; o >>= 1) { pa += __shfl_down(pa, o, 64); pc += __shfl_down(pc, o, 64); }
      if (lane == 0) { g_coefA[w] = pa * 0.125f; g_coefC[w] = pc * 0.125f; }
    }
    float* A2 = sm; float* B2 = sm + 256; float* wred = sm + 512;
    A2[t] = g_A[512 + t]; B2[t] = g_B[512 + t];
    __syncthreads();
    const int d = t;
    const float4* row = (const float4*)&outw[d*256];
    float pv[4] = {0,0,0,0}, q0 = 0.f;
    #pragma unroll 8
    for (int q = 0; q < 64; q++) {
      float4 v = row[q]; int e0 = q*4; int h = q >> 4;
      pv[h] += v.x*A2[e0] + v.y*A2[e0+1] + v.z*A2[e0+2] + v.w*A2[e0+3];
      q0    += v.x*B2[e0] + v.y*B2[e0+1] + v.z*B2[e0+2] + v.w*B2[e0+3];
    }
    q0 += outb[d];
    float c0 = linb[d] + q0;
    float Mv[6] = { linw[d], pv[0], pv[1], pv[2], pv[3], c0 };
    // 27 block-reductions via one-barrier wave partials
    float vals[27];
    { int idx = 0;
      #pragma unroll
      for (int k = 0; k < 6; k++) vals[idx++] = Mv[k];
      #pragma unroll
      for (int k = 0; k < 6; k++)
        #pragma unroll
        for (int l = 0; l < 6; l++) if (l >= k) vals[idx++] = Mv[k]*Mv[l];
    }
    #pragma unroll
    for (int k2 = 0; k2 < 27; k2++) {
      float v = vals[k2];
      #pragma unroll
      for (int o = 32; o > 0; o >>= 1) v += __shfl_down(v, o, 64);
      if (lane == 0) wred[w*27 + k2] = v;
    }
    __syncthreads();
    if (t < 27) {
      float s = wred[t] + wred[27 + t] + wred[54 + t] + wred[81 + t];
      if (t < 6) g_meanv[t] = s * (1.f/256.f);
      else {
        int p = t - 6, k = 0;
        while (p >= 6 - k) { p -= 6 - k; k++; }
        int l = k + p;
        g_G[k*6+l] = s; g_G[l*6+k] = s;
      }
    }
    #pragma unroll
    for (int k = 0; k < 6; k++) g_Vx[k*256 + d] = Mv[k] * g1[d];
    g_Vx[6*256 + d] = g1[d];
    g_Vx[7*256 + d] = b1ln[d];
  } else {
    int e = (b - 1)*256 + t;
    atomicAdd(&g_deg[edges[EE + e]], 1);
  }
}

// ===== FUSE-3: attn_m (blk 0..511) || w1v (512..543) || scan (544) || cvt (545..1952) =====
__global__ __launch_bounds__(256) void k_fuse3(const float* __restrict__ feat,
    const float* __restrict__ w1,
    const float* __restrict__ w2c, const float* __restrict__ W1c,
    const float* __restrict__ W2c, const float* __restrict__ W3c,
    const float* __restrict__ W4c) {
  __shared__ __align__(16) char smraw[34816];
  const int b = blockIdx.x, t = threadIdx.x;
  if (b < 512) {
    // ---- attn_m ----
    float* fs = (float*)smraw;                 // [4][2048]
    float* ss = fs + 8192;                     // [64][4]
    float* ww = ss + 256;                      // [64][4]
    for (int i = t; i < 2048; i += 256) {
      const float4 v = *(const float4*)&feat[i*4];
      fs[0*2048+i] = v.x; fs[1*2048+i] = v.y; fs[2*2048+i] = v.z; fs[3*2048+i] = v.w;
    }
    __syncthreads();
    int tuple = b * 64 + (t >> 2);
    int c = t & 3;
    int h = tuple & 3, f = (tuple >> 2) & 3, n = tuple >> 4;
    float fi = fs[f*2048 + n];
    float tt = g_coefA[h] * fi + g_coefC[h];
    float s = 0.f, wsum = 0.f;
    int j0 = c * 512;
    for (int j = j0; j < j0 + 512; j++) {
      float fj = fs[f*2048 + j];
      float e = __expf(tt * fj);
      s += e; wsum += e * fj;
    }
    ss[(t>>2)*4 + c] = s; ww[(t>>2)*4 + c] = wsum;
    __syncthreads();
    if (c == 0) {
      float S = ss[(t>>2)*4] + ss[(t>>2)*4+1] + ss[(t>>2)*4+2] + ss[(t>>2)*4+3];
      float W = ww[(t>>2)*4] + ww[(t>>2)*4+1] + ww[(t>>2)*4+2] + ww[(t>>2)*4+3];
      g_m[tuple] = W / S;
    }
  } else if (b < 544) {
    // ---- w1v: W1V[j][k] = W1[j,:]·Vx_k ----
    float* vx = (float*)smraw;                 // [8][256]
    #pragma unroll
    for (int k = 0; k < 8; k++) vx[k*256 + t] = g_Vx[k*256 + t];
    __syncthreads();
    int j = (b - 512)*64 + (t>>2), c = t&3;
    const float4* row = (const float4*)&w1[j*256 + c*64];
    float acc[8] = {0,0,0,0,0,0,0,0};
    #pragma unroll
    for (int q = 0; q < 16; q++) {
      float4 v = row[q]; int d0 = c*64 + q*4;
      #pragma unroll
      for (int k = 0; k < 8; k++)
        acc[k] += v.x*vx[k*256+d0] + v.y*vx[k*256+d0+1]
                + v.z*vx[k*256+d0+2] + v.w*vx[k*256+d0+3];
    }
    #pragma unroll
    for (int k = 0; k < 8; k++) acc[k] = qred(acc[k]);
    if (c == 0) {
      #pragma unroll
      for (int k = 0; k < 8; k++) g_W1V[j*8 + k] = acc[k];
    }
  } else if (b == 544) {
    // ---- scan ----
    int* wt = (int*)smraw;
    int base = t * 8;
    int v[8], ex[8], sum = 0;
    #pragma unroll
    for (int i = 0; i < 8; i++) { ex[i] = sum; v[i] = g_deg[base+i]; sum += v[i]; }
    int lane = t & 63, w = t >> 6;
    int inc = sum;
    #pragma unroll
    for (int o = 1; o < 64; o <<= 1) { int x = __shfl_up(inc, o, 64); if (lane >= o) inc += x; }
    if (lane == 63) wt[w] = inc;
    __syncthreads();
    int wb = 0;
    for (int j = 0; j < w; j++) wb += wt[j];
    int excl = wb + inc - sum;
    #pragma unroll
    for (int i = 0; i < 8; i++) {
      g_off[base+i] = excl + ex[i];
      g_dinv[base+i] = rsqrtf((float)(v[i] + 1));
    }
    if (t == 255) g_off[NN] = wb + inc;
  } else {
    // ---- cvt all weights ----
    int i = ((b - 545)*256 + t) * 4;
    const float* src; int off;
    if (i < OFF_G1)      { src = w2c; off = OFF_W2; }
    else if (i < OFF_G2) { src = W1c; off = OFF_G1; }
    else if (i < OFF_G3) { src = W2c; off = OFF_G2; }
    else if (i < OFF_G4) { src = W3c; off = OFF_G3; }
    else                 { src = W4c; off = OFF_G4; }
    float4 v = *(const float4*)&src[i - off];
    ushort4 r;
    r.x = f2bf(v.x); r.y = f2bf(v.y); r.z = f2bf(v.z); r.w = f2bf(v.w);
    *(ushort4*)&g_wbf[i] = r;
  }
}

// ================= FUSE-4: token (blk 0..511)  ||  fill (512..767) =================
__global__ __launch_bounds__(256) void k_fuse4(const float* __restrict__ feat,
    const float* __restrict__ fb1, const int* __restrict__ edges) {
  __shared__ __align__(16) float sm[2048 + 128];
  const int b = blockIdx.x, t = threadIdx.x;
  if (b < 512) {
    float* vx = sm;            // [8][256]
    float* cc = sm + 2048;     // [16][8]
    #pragma unroll
    for (int k = 0; k < 8; k++) vx[k*256 + t] = g_Vx[k*256 + t];
    if (t < 16) {
      int tok = b * 16 + t;
      int n = tok >> 2, f = tok & 3;
      float fi = feat[n*4 + f];
      float u[6] = { fi, g_m[tok*4+0], g_m[tok*4+1], g_m[tok*4+2], g_m[tok*4+3], 1.f };
      float mu = 0.f;
      #pragma unroll
      for (int k = 0; k < 6; k++) mu += g_meanv[k] * u[k];
      float q = 0.f;
      for (int k = 0; k < 6; k++)
        for (int l = 0; l < 6; l++) q += u[k] * g_G[k*6+l] * u[l];
      q *= (1.f/256.f);
      float var = q - mu * mu;
      float s = rsqrtf(var + 1e-5f);
      float c0=fi*s, c1=u[1]*s, c2=u[2]*s, c3=u[3]*s, c4=u[4]*s, c5=s, c6=-mu*s, c7=1.f;
      cc[t*8+0]=c0; cc[t*8+1]=c1; cc[t*8+2]=c2; cc[t*8+3]=c3;
      cc[t*8+4]=c4; cc[t*8+5]=c5; cc[t*8+6]=c6; cc[t*8+7]=c7;
      float4 w0; w0.x=c0; w0.y=c1; w0.z=c2; w0.w=c3;
      float4 w1v; w1v.x=c4; w1v.y=c5; w1v.z=c6; w1v.w=c7;
      *(float4*)&g_cc[tok*8]     = w0;
      *(float4*)&g_cc[tok*8 + 4] = w1v;
    }
    __syncthreads();
    int tok0 = b * 16;
    // h1 = relu(sum_k c_k W1V[j,k] + b1[j])
    for (int jj = 0; jj < 2; jj++) {
      int j0 = jj * 1024 + t * 4;
      float4 w0[4], w1r[4];
      #pragma unroll
      for (int qj = 0; qj < 4; qj++) {
        w0[qj]  = *(const float4*)&g_W1V[(j0+qj)*8];
        w1r[qj] = *(const float4*)&g_W1V[(j0+qj)*8 + 4];
      }
      const float4 bb = *(const float4*)&fb1[j0];
      for (int tt2 = 0; tt2 < 16; tt2++) {
        float c0=cc[tt2*8+0], c1=cc[tt2*8+1], c2=cc[tt2*8+2], c3=cc[tt2*8+3];
        float c4=cc[tt2*8+4], c5=cc[tt2*8+5], c6=cc[tt2*8+6], c7=cc[tt2*8+7];
        float4 hv;
        hv.x = bb.x + c0*w0[0].x + c1*w0[0].y + c2*w0[0].z + c3*w0[0].w
                    + c4*w1r[0].x + c5*w1r[0].y + c6*w1r[0].z + c7*w1r[0].w;
        hv.y = bb.y + c0*w0[1].x + c1*w0[1].y + c2*w0[1].z + c3*w0[1].w
                    + c4*w1r[1].x + c5*w1r[1].y + c6*w1r[1].z + c7*w1r[1].w;
        hv.z = bb.z + c0*w0[2].x + c1*w0[2].y + c2*w0[2].z + c3*w0[2].w
                    + c4*w1r[2].x + c5*w1r[2].y + c6*w1r[2].z + c7*w1r[2].w;
        hv.w = bb.w + c0*w0[3].x + c1*w0[3].y + c2*w0[3].z + c3*w0[3].w
                    + c4*w1r[3].x + c5*w1r[3].y + c6*w1r[3].z + c7*w1r[3].w;
        ushort4 hu;
        hu.x = f2bf(fmaxf(hv.x, 0.f)); hu.y = f2bf(fmaxf(hv.y, 0.f));
        hu.z = f2bf(fmaxf(hv.z, 0.f)); hu.w = f2bf(fmaxf(hv.w, 0.f));
        *(ushort4*)&g_h1h[(size_t)(tok0 + tt2)*2048 + j0] = hu;
      }
    }
  } else {
    int e = (b - 512)*256 + t;
    int s = edges[e], d = edges[EE + e];
    int pos = atomicAdd(&g_cur[d], 1);
    g_adj[g_off[d] + pos] = s;
  }
}

// ---------------- bf16 MFMA GEMM: C[M,N] = A[M,K] @ B[N,K]^T ----------------
template<int DO_ROWSCALE, int OUT_BF16, int HAS_BIAS>
__global__ __launch_bounds__(256) void k_mm64(
    const u16* __restrict__ A, const u16* __restrict__ Bm, void* __restrict__ Cv,
    int M, int N, int K,
    const float* __restrict__ rowscale, const float* __restrict__ bias)
{
  __shared__ u16 Asl[64*64];
  __shared__ u16 Bsl[64*64];
  const int t = threadIdx.x;
  const int w = t >> 6, lane = t & 63;
  const int bm = blockIdx.y * 64, bn = blockIdx.x * 64;
  const int wr = w >> 1, wc = w & 1;
  const int fr = lane & 15;
  const int gk = lane >> 4;
  const int sslot = lane & 7;
  f32x4 acc[2][2] = {};
  for (int k0 = 0; k0 < K; k0 += 64) {
    #pragma unroll
    for (int c = 0; c < 2; c++) {
      int r = (w << 4) + (c << 3) + (lane >> 3);
      int ks = ((sslot ^ (r & 7)) << 3);
      gl_lds16(A  + (size_t)(bm + r)*K + k0 + ks, Asl + (w << 10) + (c << 9));
      gl_lds16(Bm + (size_t)(bn + r)*K + k0 + ks, Bsl + (w << 10) + (c << 9));
    }
    __syncthreads();
    bf16x8 af[2][2], bfv[2][2];
    #pragma unroll
    for (int rb = 0; rb < 2; rb++) {
      int row = wr*32 + rb*16 + fr;
      #pragma unroll
      for (int kk = 0; kk < 2; kk++) {
        int q = (kk << 2) + gk;
        af[rb][kk] = *(const bf16x8*)&Asl[(row << 6) + ((q ^ (row & 7)) << 3)];
      }
    }
    #pragma unroll
    for (int nb = 0; nb < 2; nb++) {
      int col = wc*32 + nb*16 + fr;
      #pragma unroll
      for (int kk = 0; kk < 2; kk++) {
        int q = (kk << 2) + gk;
        bfv[nb][kk] = *(const bf16x8*)&Bsl[(col << 6) + ((q ^ (col & 7)) << 3)];
      }
    }
    #pragma unroll
    for (int kk = 0; kk < 2; kk++)
      #pragma unroll
      for (int rb = 0; rb < 2; rb++)
        #pragma unroll
        for (int nb = 0; nb < 2; nb++)
          acc[rb][nb] = __builtin_amdgcn_mfma_f32_16x16x32_bf16(af[rb][kk], bfv[nb][kk], acc[rb][nb], 0, 0, 0);
    __syncthreads();
  }
  #pragma unroll
  for (int rb = 0; rb < 2; rb++) {
    #pragma unroll
    for (int r = 0; r < 4; r++) {
      int row = bm + wr*32 + rb*16 + gk*4 + r;
      float rs = DO_ROWSCALE ? rowscale[row] : 1.f;
      #pragma unroll
      for (int nb = 0; nb < 2; nb++) {
        int col = bn + wc*32 + nb*16 + fr;
        float v = acc[rb][nb][r];
        if (HAS_BIAS) v += bias[col];
        if (DO_ROWSCALE) v *= rs;
        if (OUT_BF16) ((u16*)Cv)[(size_t)row*N + col] = f2bf(v);
        else ((float*)Cv)[(size_t)row*N + col] = v;
      }
    }
  }
}

// ---------------- K6: LN2 + mean + relu -> bf16 (x1 rebuilt from cc) ----------------
__global__ __launch_bounds__(256) void k_ln2(const float* __restrict__ g2,
                                             const float* __restrict__ b2ln) {
  __shared__ __align__(16) float vx[2048];
  __shared__ float red[8];
  int n = blockIdx.x, t = threadIdx.x;
  #pragma unroll
  for (int k = 0; k < 8; k++) vx[k*256 + t] = g_Vx[k*256 + t];
  __syncthreads();
  int lane = t & 63, w = t >> 6;
  float acc = 0.f;
  for (int f = 0; f < 4; f++) {
    int tok = n*4 + f;
    float c[8];
    #pragma unroll
    for (int k = 0; k < 8; k++) c[k] = g_cc[tok*8 + k];
    float x1 = 0.f;
    #pragma unroll
    for (int k = 0; k < 8; k++) x1 += c[k] * vx[k*256 + t];
    float v = x1 + g_ff[tok*256 + t];
    float s1 = v, s2 = v*v;
    #pragma unroll
    for (int o = 32; o > 0; o >>= 1) { s1 += __shfl_down(s1, o, 64); s2 += __shfl_down(s2, o, 64); }
    __syncthreads();
    if (lane == 0) { red[w*2] = s1; red[w*2+1] = s2; }
    __syncthreads();
    float S1 = red[0] + red[2] + red[4] + red[6];
    float S2 = red[1] + red[3] + red[5] + red[7];
    float mu = S1 * (1.f/256.f);
    float var = S2 * (1.f/256.f) - mu*mu;
    float x2 = (v - mu) * rsqrtf(var + 1e-5f) * g2[t] + b2ln[t];
    acc += x2;
  }
  g_xmh[n*256 + t] = f2bf(fmaxf(acc * 0.25f, 0.f));
}

// ---------------- GCN aggregation: wave-per-node, uint4 gathers ----------------
template<int OUT_BF16, int DO_RELU>
__global__ __launch_bounds__(256) void k_agg(const float* __restrict__ bias,
                                             void* __restrict__ outv) {
  const int t = threadIdx.x, w = t >> 6, lane = t & 63;
  const int i = blockIdx.x*4 + w;
  const int d = lane * 8;
  const uint4* tbl = (const uint4*)g_hsh;
  float a[8] = {0,0,0,0,0,0,0,0};
  acc8(tbl[i*64 + lane], a);
  int e0 = g_off[i], e1 = g_off[i+1];
  int e = e0;
  for (; e + 4 <= e1; e += 4) {
    int s0 = g_adj[e+0], s1 = g_adj[e+1], s2 = g_adj[e+2], s3 = g_adj[e+3];
    uint4 v0 = tbl[s0*64 + lane];
    uint4 v1 = tbl[s1*64 + lane];
    uint4 v2 = tbl[s2*64 + lane];
    uint4 v3 = tbl[s3*64 + lane];
    acc8(v0, a); acc8(v1, a); acc8(v2, a); acc8(v3, a);
  }
  for (; e < e1; e++) acc8(tbl[g_adj[e]*64 + lane], a);
  float di = g_dinv[i];
  const float4 b0 = *(const float4*)&bias[d];
  const float4 b1 = *(const float4*)&bias[d+4];
  a[0]=di*a[0]+b0.x; a[1]=di*a[1]+b0.y; a[2]=di*a[2]+b0.z; a[3]=di*a[3]+b0.w;
  a[4]=di*a[4]+b1.x; a[5]=di*a[5]+b1.y; a[6]=di*a[6]+b1.z; a[7]=di*a[7]+b1.w;
  if (DO_RELU) {
    #pragma unroll
    for (int q = 0; q < 8; q++) a[q] = fmaxf(a[q], 0.f);
  }
  if (OUT_BF16) {
    uint4 r;
    r.x = ((u32)f2bf(a[1])<<16) | f2bf(a[0]);
    r.y = ((u32)f2bf(a[3])<<16) | f2bf(a[2]);
    r.z = ((u32)f2bf(a[5])<<16) | f2bf(a[4]);
    r.w = ((u32)f2bf(a[7])<<16) | f2bf(a[6]);
    *(uint4*)&((u16*)outv)[i*512 + d] = r;
  } else {
    float4 r0; r0.x=a[0]; r0.y=a[1]; r0.z=a[2]; r0.w=a[3];
    float4 r1; r1.x=a[4]; r1.y=a[5]; r1.z=a[6]; r1.w=a[7];
    *(float4*)&((float*)outv)[i*512 + d]     = r0;
    *(float4*)&((float*)outv)[i*512 + d + 4] = r1;
  }
}

// ---------------- host ----------------
static float* symf(const void* s) { void* p = nullptr; (void)hipGetSymbolAddress(&p, s); return (float*)p; }

extern "C" void kernel_launch(void* const* d_in, const int* in_sizes, int n_in,
                              void* d_out, int out_size, void* d_ws, size_t ws_size,
                              hipStream_t stream) {
  const float* feat = (const float*)d_in[0];
  const int*   edges= (const int*)  d_in[1];
  const float* linw = (const float*)d_in[2];
  const float* linb = (const float*)d_in[3];
  const float* ipw  = (const float*)d_in[4];
  const float* ipb  = (const float*)d_in[5];
  const float* outw = (const float*)d_in[6];
  const float* outb = (const float*)d_in[7];
  const float* ln1g = (const float*)d_in[8];
  const float* ln1b = (const float*)d_in[9];
  const float* fw1  = (const float*)d_in[10];
  const float* fb1  = (const float*)d_in[11];
  const float* fw2  = (const float*)d_in[12];
  const float* fb2  = (const float*)d_in[13];
  const float* ln2g = (const float*)d_in[14];
  const float* ln2b = (const float*)d_in[15];
  const float* W1g  = (const float*)d_in[16];
  const float* b1g  = (const float*)d_in[17];
  const float* W2g  = (const float*)d_in[18];
  const float* b2g  = (const float*)d_in[19];
  const float* W3g  = (const float*)d_in[20];
  const float* b3g  = (const float*)d_in[21];
  const float* W4g  = (const float*)d_in[22];
  const float* b4g  = (const float*)d_in[23];
  float* out = (float*)d_out;

  u16*   p_h1h = (u16*)symf(HIP_SYMBOL(g_h1h));
  float* p_ff  = symf(HIP_SYMBOL(g_ff));
  u16*   p_xmh = (u16*)symf(HIP_SYMBOL(g_xmh));
  u16*   p_hsh = (u16*)symf(HIP_SYMBOL(g_hsh));
  u16*   p_xgh = (u16*)symf(HIP_SYMBOL(g_xgh));
  u16*   p_wbf = (u16*)symf(HIP_SYMBOL(g_wbf));
  float* p_dinv= symf(HIP_SYMBOL(g_dinv));

  // fused prep pipeline
  k_fuse1<<<20,   256, 0, stream>>>(ipw, ipb, linw, linb);
  k_fuse2<<<257,  256, 0, stream>>>(outw, outb, linw, linb, ln1g, ln1b, edges);
  k_fuse3<<<1953, 256, 0, stream>>>(feat, fw1, fw2, W1g, W2g, W3g, W4g);
  k_fuse4<<<768,  256, 0, stream>>>(feat, fb1, edges);

  // FFN2: ff = h1 @ W2^T + b2 (bf16 MFMA, fp32 out)
  k_mm64<0,0,1><<<dim3(256/64, NT/64), 256, 0, stream>>>(
      p_h1h, p_wbf + OFF_W2, p_ff, NT, 256, 2048, nullptr, fb2);
  k_ln2<<<NN, 256, 0, stream>>>(ln2g, ln2b);

  // GCN layers
  k_mm64<1,1,0><<<dim3(8, 32), 256, 0, stream>>>(
      p_xmh, p_wbf + OFF_G1, p_hsh, NN, 512, 256, p_dinv, nullptr);
  k_agg<1,1><<<NN/4, 256, 0, stream>>>(b1g, p_xgh);
  k_mm64<1,1,0><<<dim3(8, 32), 256, 0, stream>>>(
      p_xgh, p_wbf + OFF_G2, p_hsh, NN, 512, 512, p_dinv, nullptr);
  k_agg<1,1><<<NN/4, 256, 0, stream>>>(b2g, p_xgh);
  k_mm64<1,1,0><<<dim3(8, 32), 256, 0, stream>>>(
      p_xgh, p_wbf + OFF_G3, p_hsh, NN, 512, 512, p_dinv, nullptr);
  k_agg<1,1><<<NN/4, 256, 0, stream>>>(b3g, p_xgh);
  k_mm64<1,1,0><<<dim3(8, 32), 256, 0, stream>>>(
      p_xgh, p_wbf + OFF_G4, p_hsh, NN, 512, 512, p_dinv, nullptr);
  k_agg<0,0><<<NN/4, 256, 0, stream>>>(b4g, out);
}

// Round 6
// 202.755 us; speedup vs baseline: 2.1149x; 1.0408x over previous
//
#include <hip/hip_runtime.h>
#include <hip/hip_bf16.h>
#include <math.h>

// Problem constants
#define NN   2048
#define FB   4
#define DD   256
#define EE   65536
#define NT   (NN*FB)
#define FFD  2048

typedef unsigned int u32;
typedef unsigned short u16;
typedef __attribute__((ext_vector_type(4))) float f32x4;
typedef __attribute__((ext_vector_type(8))) short bf16x8;

// weight buffer offsets (bf16 elements)
#define OFF_W2   0
#define OFF_G1   524288
#define OFF_G2   655360
#define OFF_G3   917504
#define OFF_G4   1179648
#define WBF_TOT  1441792

// ---------------- static device scratch ----------------
__device__ float g_A[768], g_B[768];
__device__ float g_coefA[4], g_coefC[4];
__device__ float g_meanv[6], g_G[36];
__device__ float g_Vx[8*DD];
__device__ float g_W1V[FFD*8];
__device__ float g_m[NT*4];
__device__ float g_cc[NT*8];                // per-token LN1 coefficients
__device__ u16   g_h1h[(size_t)NT*FFD];     // h1 in bf16 (32 MB)
__device__ float g_ff[NT*DD];
__device__ u16   g_xmh[NN*DD];              // GCN input bf16
__device__ u16   g_hsh[NN*512];             // per-layer transformed bf16 (2 MB, L2-resident)
__device__ u16   g_xgh[NN*512];             // per-layer activations bf16
__device__ u16   g_wbf[WBF_TOT];            // all GEMM weights bf16
__device__ int   g_deg[NN], g_off[NN+1], g_cur[NN], g_adj[EE];
__device__ float g_dinv[NN];

// ---------------- helpers ----------------
__device__ __forceinline__ u16 f2bf(float x) {
  u32 u = __float_as_uint(x);
  return (u16)((u + 0x7FFFu + ((u >> 16) & 1u)) >> 16);
}
__device__ __forceinline__ float bf2f(u16 x) {
  return __uint_as_float(((u32)x) << 16);
}
__device__ __forceinline__ void gl_lds16(const void* g, void* l) {
  __builtin_amdgcn_global_load_lds(
      (const __attribute__((address_space(1))) u32*)g,
      (__attribute__((address_space(3))) u32*)l, 16, 0, 0);
}
__device__ __forceinline__ float qred(float v) {   // reduce across 4-lane quad
  v += __shfl_xor(v, 1, 64);
  v += __shfl_xor(v, 2, 64);
  return v;
}
__device__ __forceinline__ void acc8(const uint4 v, float* a) {
  a[0]+=__uint_as_float(v.x<<16); a[1]+=__uint_as_float(v.x&0xffff0000u);
  a[2]+=__uint_as_float(v.y<<16); a[3]+=__uint_as_float(v.y&0xffff0000u);
  a[4]+=__uint_as_float(v.z<<16); a[5]+=__uint_as_float(v.z&0xffff0000u);
  a[6]+=__uint_as_float(v.w<<16); a[7]+=__uint_as_float(v.w&0xffff0000u);
}

// ================= FUSE-1: prep_ab (blk 0..11)  ||  zero (blk 12..19) =================
__global__ __launch_bounds__(256) void k_fuse1(const float* __restrict__ ipw,
    const float* __restrict__ ipb, const float* __restrict__ linw,
    const float* __restrict__ linb) {
  __shared__ __align__(16) float sm[512];
  const int b = blockIdx.x, t = threadIdx.x;
  if (b < 12) {
    float* lw = sm; float* lb = sm + 256;
    lw[t] = linw[t]; lb[t] = linb[t];
    __syncthreads();
    int j = b*64 + (t>>2), c = t&3;
    const float4* row = (const float4*)&ipw[j*256 + c*64];
    float a = 0.f, bb = 0.f;
    #pragma unroll
    for (int q = 0; q < 16; q++) {
      float4 v = row[q]; int d0 = c*64 + q*4;
      a  += v.x*lw[d0] + v.y*lw[d0+1] + v.z*lw[d0+2] + v.w*lw[d0+3];
      bb += v.x*lb[d0] + v.y*lb[d0+1] + v.z*lb[d0+2] + v.w*lb[d0+3];
    }
    a = qred(a); bb = qred(bb);
    if (c == 0) { g_A[j] = a; g_B[j] = bb + ipb[j]; }
  } else {
    int i = (b - 12)*256 + t;
    if (i < NN) { g_deg[i] = 0; g_cur[i] = 0; }
  }
}

// ================= FUSE-2: prep_head (blk 0)  ||  deg (blk 1..256) =================
__global__ __launch_bounds__(256) void k_fuse2(const float* __restrict__ outw,
    const float* __restrict__ outb, const float* __restrict__ linw,
    const float* __restrict__ linb, const float* __restrict__ g1,
    const float* __restrict__ b1ln, const int* __restrict__ edges) {
  __shared__ __align__(16) float sm[512 + 4*27];
  const int b = blockIdx.x, t = threadIdx.x;
  if (b == 0) {
    int lane = t & 63, w = t >> 6;
    {
      float aq = g_A[w*64 + lane], ak = g_A[256 + w*64 + lane], bq = g_B[w*64 + lane];
      float pa = aq * ak, pc = bq * ak;
      #pragma unroll
      for (int o = 32; o > 0; o >>= 1) { pa += __shfl_down(pa, o, 64); pc += __shfl_down(pc, o, 64); }
      if (lane == 0) { g_coefA[w] = pa * 0.125f; g_coefC[w] = pc * 0.125f; }
    }
    float* A2 = sm; float* B2 = sm + 256; float* wred = sm + 512;
    A2[t] = g_A[512 + t]; B2[t] = g_B[512 + t];
    __syncthreads();
    const int d = t;
    const float4* row = (const float4*)&outw[d*256];
    float pv[4] = {0,0,0,0}, q0 = 0.f;
    #pragma unroll 8
    for (int q = 0; q < 64; q++) {
      float4 v = row[q]; int e0 = q*4; int h = q >> 4;
      pv[h] += v.x*A2[e0] + v.y*A2[e0+1] + v.z*A2[e0+2] + v.w*A2[e0+3];
      q0    += v.x*B2[e0] + v.y*B2[e0+1] + v.z*B2[e0+2] + v.w*B2[e0+3];
    }
    q0 += outb[d];
    float c0 = linb[d] + q0;
    float Mv[6] = { linw[d], pv[0], pv[1], pv[2], pv[3], c0 };
    float vals[27];
    { int idx = 0;
      #pragma unroll
      for (int k = 0; k < 6; k++) vals[idx++] = Mv[k];
      #pragma unroll
      for (int k = 0; k < 6; k++)
        #pragma unroll
        for (int l = 0; l < 6; l++) if (l >= k) vals[idx++] = Mv[k]*Mv[l];
    }
    #pragma unroll
    for (int k2 = 0; k2 < 27; k2++) {
      float v = vals[k2];
      #pragma unroll
      for (int o = 32; o > 0; o >>= 1) v += __shfl_down(v, o, 64);
      if (lane == 0) wred[w*27 + k2] = v;
    }
    __syncthreads();
    if (t < 27) {
      float s = wred[t] + wred[27 + t] + wred[54 + t] + wred[81 + t];
      if (t < 6) g_meanv[t] = s * (1.f/256.f);
      else {
        int p = t - 6, k = 0;
        while (p >= 6 - k) { p -= 6 - k; k++; }
        int l = k + p;
        g_G[k*6+l] = s; g_G[l*6+k] = s;
      }
    }
    #pragma unroll
    for (int k = 0; k < 6; k++) g_Vx[k*256 + d] = Mv[k] * g1[d];
    g_Vx[6*256 + d] = g1[d];
    g_Vx[7*256 + d] = b1ln[d];
  } else {
    int e = (b - 1)*256 + t;
    atomicAdd(&g_deg[edges[EE + e]], 1);
  }
}

// ===== FUSE-3: attn_m (blk 0..511) || w1v (512..543) || scan (544) || cvt (545..1952) =====
__global__ __launch_bounds__(256) void k_fuse3(const float* __restrict__ feat,
    const float* __restrict__ w1,
    const float* __restrict__ w2c, const float* __restrict__ W1c,
    const float* __restrict__ W2c, const float* __restrict__ W3c,
    const float* __restrict__ W4c) {
  __shared__ __align__(16) char smraw[34816];
  const int b = blockIdx.x, t = threadIdx.x;
  if (b < 512) {
    // ---- attn_m ----
    float* fs = (float*)smraw;                 // [4][2048]
    float* ss = fs + 8192;                     // [64][4]
    float* ww = ss + 256;                      // [64][4]
    for (int i = t; i < 2048; i += 256) {
      const float4 v = *(const float4*)&feat[i*4];
      fs[0*2048+i] = v.x; fs[1*2048+i] = v.y; fs[2*2048+i] = v.z; fs[3*2048+i] = v.w;
    }
    __syncthreads();
    int tuple = b * 64 + (t >> 2);
    int c = t & 3;
    int h = tuple & 3, f = (tuple >> 2) & 3, n = tuple >> 4;
    float fi = fs[f*2048 + n];
    float tt = g_coefA[h] * fi + g_coefC[h];
    float s = 0.f, wsum = 0.f;
    int j0 = c * 512;
    for (int j = j0; j < j0 + 512; j++) {
      float fj = fs[f*2048 + j];
      float e = __expf(tt * fj);
      s += e; wsum += e * fj;
    }
    ss[(t>>2)*4 + c] = s; ww[(t>>2)*4 + c] = wsum;
    __syncthreads();
    if (c == 0) {
      float S = ss[(t>>2)*4] + ss[(t>>2)*4+1] + ss[(t>>2)*4+2] + ss[(t>>2)*4+3];
      float W = ww[(t>>2)*4] + ww[(t>>2)*4+1] + ww[(t>>2)*4+2] + ww[(t>>2)*4+3];
      g_m[tuple] = W / S;
    }
  } else if (b < 544) {
    // ---- w1v: W1V[j][k] = W1[j,:]·Vx_k ----
    float* vx = (float*)smraw;                 // [8][256]
    #pragma unroll
    for (int k = 0; k < 8; k++) vx[k*256 + t] = g_Vx[k*256 + t];
    __syncthreads();
    int j = (b - 512)*64 + (t>>2), c = t&3;
    const float4* row = (const float4*)&w1[j*256 + c*64];
    float acc[8] = {0,0,0,0,0,0,0,0};
    #pragma unroll
    for (int q = 0; q < 16; q++) {
      float4 v = row[q]; int d0 = c*64 + q*4;
      #pragma unroll
      for (int k = 0; k < 8; k++)
        acc[k] += v.x*vx[k*256+d0] + v.y*vx[k*256+d0+1]
                + v.z*vx[k*256+d0+2] + v.w*vx[k*256+d0+3];
    }
    #pragma unroll
    for (int k = 0; k < 8; k++) acc[k] = qred(acc[k]);
    if (c == 0) {
      #pragma unroll
      for (int k = 0; k < 8; k++) g_W1V[j*8 + k] = acc[k];
    }
  } else if (b == 544) {
    // ---- scan ----
    int* wt = (int*)smraw;
    int base = t * 8;
    int v[8], ex[8], sum = 0;
    #pragma unroll
    for (int i = 0; i < 8; i++) { ex[i] = sum; v[i] = g_deg[base+i]; sum += v[i]; }
    int lane = t & 63, w = t >> 6;
    int inc = sum;
    #pragma unroll
    for (int o = 1; o < 64; o <<= 1) { int x = __shfl_up(inc, o, 64); if (lane >= o) inc += x; }
    if (lane == 63) wt[w] = inc;
    __syncthreads();
    int wb = 0;
    for (int j = 0; j < w; j++) wb += wt[j];
    int excl = wb + inc - sum;
    #pragma unroll
    for (int i = 0; i < 8; i++) {
      g_off[base+i] = excl + ex[i];
      g_dinv[base+i] = rsqrtf((float)(v[i] + 1));
    }
    if (t == 255) g_off[NN] = wb + inc;
  } else {
    // ---- cvt all weights ----
    int i = ((b - 545)*256 + t) * 4;
    const float* src; int off;
    if (i < OFF_G1)      { src = w2c; off = OFF_W2; }
    else if (i < OFF_G2) { src = W1c; off = OFF_G1; }
    else if (i < OFF_G3) { src = W2c; off = OFF_G2; }
    else if (i < OFF_G4) { src = W3c; off = OFF_G3; }
    else                 { src = W4c; off = OFF_G4; }
    float4 v = *(const float4*)&src[i - off];
    ushort4 r;
    r.x = f2bf(v.x); r.y = f2bf(v.y); r.z = f2bf(v.z); r.w = f2bf(v.w);
    *(ushort4*)&g_wbf[i] = r;
  }
}

// ================= FUSE-4: token/h1 (blk 0..511)  ||  fill (512..767) =================
// token blocks: 16 tokens each; thread owns j0=t*8 output columns; W1V in regs;
// 16 B coalesced stores.
__global__ __launch_bounds__(256) void k_fuse4(const float* __restrict__ feat,
    const float* __restrict__ fb1, const int* __restrict__ edges) {
  __shared__ __align__(16) float cc[16*8];
  const int b = blockIdx.x, t = threadIdx.x;
  if (b < 512) {
    if (t < 16) {
      int tok = b * 16 + t;
      int n = tok >> 2, f = tok & 3;
      float fi = feat[n*4 + f];
      float u[6] = { fi, g_m[tok*4+0], g_m[tok*4+1], g_m[tok*4+2], g_m[tok*4+3], 1.f };
      float mu = 0.f;
      #pragma unroll
      for (int k = 0; k < 6; k++) mu += g_meanv[k] * u[k];
      float q = 0.f;
      for (int k = 0; k < 6; k++)
        for (int l = 0; l < 6; l++) q += u[k] * g_G[k*6+l] * u[l];
      q *= (1.f/256.f);
      float var = q - mu * mu;
      float s = rsqrtf(var + 1e-5f);
      float c0=fi*s, c1=u[1]*s, c2=u[2]*s, c3=u[3]*s, c4=u[4]*s, c5=s, c6=-mu*s, c7=1.f;
      cc[t*8+0]=c0; cc[t*8+1]=c1; cc[t*8+2]=c2; cc[t*8+3]=c3;
      cc[t*8+4]=c4; cc[t*8+5]=c5; cc[t*8+6]=c6; cc[t*8+7]=c7;
      float4 w0; w0.x=c0; w0.y=c1; w0.z=c2; w0.w=c3;
      float4 w1v; w1v.x=c4; w1v.y=c5; w1v.z=c6; w1v.w=c7;
      *(float4*)&g_cc[tok*8]     = w0;
      *(float4*)&g_cc[tok*8 + 4] = w1v;
    }
    __syncthreads();
    const int j0 = t * 8;
    // W1V rows j0..j0+7 into registers (fp32, exact)
    float w[8][8];
    #pragma unroll
    for (int q = 0; q < 8; q++) {
      float4 a0 = *(const float4*)&g_W1V[(j0+q)*8];
      float4 a1 = *(const float4*)&g_W1V[(j0+q)*8 + 4];
      w[q][0]=a0.x; w[q][1]=a0.y; w[q][2]=a0.z; w[q][3]=a0.w;
      w[q][4]=a1.x; w[q][5]=a1.y; w[q][6]=a1.z; w[q][7]=a1.w;
    }
    float bv[8];
    { float4 b0 = *(const float4*)&fb1[j0];
      float4 b1 = *(const float4*)&fb1[j0+4];
      bv[0]=b0.x; bv[1]=b0.y; bv[2]=b0.z; bv[3]=b0.w;
      bv[4]=b1.x; bv[5]=b1.y; bv[6]=b1.z; bv[7]=b1.w; }
    const int tok0 = b * 16;
    for (int tk = 0; tk < 16; tk++) {
      float c0=cc[tk*8+0], c1=cc[tk*8+1], c2=cc[tk*8+2], c3=cc[tk*8+3];
      float c4=cc[tk*8+4], c5=cc[tk*8+5], c6=cc[tk*8+6], c7=cc[tk*8+7];
      u16 h[8];
      #pragma unroll
      for (int q = 0; q < 8; q++) {
        float v = bv[q] + c0*w[q][0] + c1*w[q][1] + c2*w[q][2] + c3*w[q][3]
                        + c4*w[q][4] + c5*w[q][5] + c6*w[q][6] + c7*w[q][7];
        h[q] = f2bf(fmaxf(v, 0.f));
      }
      uint4 r;
      r.x = ((u32)h[1]<<16) | h[0];
      r.y = ((u32)h[3]<<16) | h[2];
      r.z = ((u32)h[5]<<16) | h[4];
      r.w = ((u32)h[7]<<16) | h[6];
      *(uint4*)&g_h1h[(size_t)(tok0 + tk)*2048 + j0] = r;
    }
  } else {
    int e = (b - 512)*256 + t;
    int s = edges[e], d = edges[EE + e];
    int pos = atomicAdd(&g_cur[d], 1);
    g_adj[g_off[d] + pos] = s;
  }
}

// ---------------- bf16 MFMA GEMM: C[M,N] = A[M,K] @ B[N,K]^T ----------------
template<int DO_ROWSCALE, int OUT_BF16, int HAS_BIAS>
__global__ __launch_bounds__(256) void k_mm64(
    const u16* __restrict__ A, const u16* __restrict__ Bm, void* __restrict__ Cv,
    int M, int N, int K,
    const float* __restrict__ rowscale, const float* __restrict__ bias)
{
  __shared__ u16 Asl[64*64];
  __shared__ u16 Bsl[64*64];
  const int t = threadIdx.x;
  const int w = t >> 6, lane = t & 63;
  const int bm = blockIdx.y * 64, bn = blockIdx.x * 64;
  const int wr = w >> 1, wc = w & 1;
  const int fr = lane & 15;
  const int gk = lane >> 4;
  const int sslot = lane & 7;
  f32x4 acc[2][2] = {};
  for (int k0 = 0; k0 < K; k0 += 64) {
    #pragma unroll
    for (int c = 0; c < 2; c++) {
      int r = (w << 4) + (c << 3) + (lane >> 3);
      int ks = ((sslot ^ (r & 7)) << 3);
      gl_lds16(A  + (size_t)(bm + r)*K + k0 + ks, Asl + (w << 10) + (c << 9));
      gl_lds16(Bm + (size_t)(bn + r)*K + k0 + ks, Bsl + (w << 10) + (c << 9));
    }
    __syncthreads();
    bf16x8 af[2][2], bfv[2][2];
    #pragma unroll
    for (int rb = 0; rb < 2; rb++) {
      int row = wr*32 + rb*16 + fr;
      #pragma unroll
      for (int kk = 0; kk < 2; kk++) {
        int q = (kk << 2) + gk;
        af[rb][kk] = *(const bf16x8*)&Asl[(row << 6) + ((q ^ (row & 7)) << 3)];
      }
    }
    #pragma unroll
    for (int nb = 0; nb < 2; nb++) {
      int col = wc*32 + nb*16 + fr;
      #pragma unroll
      for (int kk = 0; kk < 2; kk++) {
        int q = (kk << 2) + gk;
        bfv[nb][kk] = *(const bf16x8*)&Bsl[(col << 6) + ((q ^ (col & 7)) << 3)];
      }
    }
    #pragma unroll
    for (int kk = 0; kk < 2; kk++)
      #pragma unroll
      for (int rb = 0; rb < 2; rb++)
        #pragma unroll
        for (int nb = 0; nb < 2; nb++)
          acc[rb][nb] = __builtin_amdgcn_mfma_f32_16x16x32_bf16(af[rb][kk], bfv[nb][kk], acc[rb][nb], 0, 0, 0);
    __syncthreads();
  }
  #pragma unroll
  for (int rb = 0; rb < 2; rb++) {
    #pragma unroll
    for (int r = 0; r < 4; r++) {
      int row = bm + wr*32 + rb*16 + gk*4 + r;
      float rs = DO_ROWSCALE ? rowscale[row] : 1.f;
      #pragma unroll
      for (int nb = 0; nb < 2; nb++) {
        int col = bn + wc*32 + nb*16 + fr;
        float v = acc[rb][nb][r];
        if (HAS_BIAS) v += bias[col];
        if (DO_ROWSCALE) v *= rs;
        if (OUT_BF16) ((u16*)Cv)[(size_t)row*N + col] = f2bf(v);
        else ((float*)Cv)[(size_t)row*N + col] = v;
      }
    }
  }
}

// ---------------- K6: LN2 + mean + relu -> bf16 (wave-per-f, 2 barriers) ----------------
__global__ __launch_bounds__(256) void k_ln2(const float* __restrict__ g2,
                                             const float* __restrict__ b2ln) {
  __shared__ __align__(16) float vx[2048];
  __shared__ __align__(16) float xs[4*256];
  const int n = blockIdx.x, t = threadIdx.x;
  #pragma unroll
  for (int k = 0; k < 8; k++) vx[k*256 + t] = g_Vx[k*256 + t];
  __syncthreads();
  const int f = t >> 6, lane = t & 63;
  const int tok = n*4 + f;
  const int d0 = lane * 4;
  float c[8];
  { float4 c0 = *(const float4*)&g_cc[tok*8];
    float4 c1 = *(const float4*)&g_cc[tok*8 + 4];
    c[0]=c0.x; c[1]=c0.y; c[2]=c0.z; c[3]=c0.w;
    c[4]=c1.x; c[5]=c1.y; c[6]=c1.z; c[7]=c1.w; }
  float4 ffv = *(const float4*)&g_ff[tok*256 + d0];
  float v[4];
  #pragma unroll
  for (int j = 0; j < 4; j++) {
    float x1 = 0.f;
    #pragma unroll
    for (int k = 0; k < 8; k++) x1 += c[k] * vx[k*256 + d0 + j];
    v[j] = x1;
  }
  v[0] += ffv.x; v[1] += ffv.y; v[2] += ffv.z; v[3] += ffv.w;
  float s1 = v[0]+v[1]+v[2]+v[3];
  float s2 = v[0]*v[0]+v[1]*v[1]+v[2]*v[2]+v[3]*v[3];
  #pragma unroll
  for (int o = 32; o > 0; o >>= 1) { s1 += __shfl_down(s1, o, 64); s2 += __shfl_down(s2, o, 64); }
  s1 = __shfl(s1, 0, 64); s2 = __shfl(s2, 0, 64);
  float mu = s1 * (1.f/256.f);
  float var = s2 * (1.f/256.f) - mu*mu;
  float inv = rsqrtf(var + 1e-5f);
  float4 gg = *(const float4*)&g2[d0];
  float4 bb = *(const float4*)&b2ln[d0];
  float4 x2;
  x2.x = (v[0]-mu)*inv*gg.x + bb.x;
  x2.y = (v[1]-mu)*inv*gg.y + bb.y;
  x2.z = (v[2]-mu)*inv*gg.z + bb.z;
  x2.w = (v[3]-mu)*inv*gg.w + bb.w;
  *(float4*)&xs[f*256 + d0] = x2;
  __syncthreads();
  if (t < 64) {
    int dd = t * 4;
    float4 a0 = *(const float4*)&xs[0*256 + dd];
    float4 a1 = *(const float4*)&xs[1*256 + dd];
    float4 a2 = *(const float4*)&xs[2*256 + dd];
    float4 a3 = *(const float4*)&xs[3*256 + dd];
    float r0 = fmaxf((a0.x+a1.x+a2.x+a3.x)*0.25f, 0.f);
    float r1 = fmaxf((a0.y+a1.y+a2.y+a3.y)*0.25f, 0.f);
    float r2 = fmaxf((a0.z+a1.z+a2.z+a3.z)*0.25f, 0.f);
    float r3 = fmaxf((a0.w+a1.w+a2.w+a3.w)*0.25f, 0.f);
    ushort4 r;
    r.x = f2bf(r0); r.y = f2bf(r1); r.z = f2bf(r2); r.w = f2bf(r3);
    *(ushort4*)&g_xmh[n*256 + dd] = r;
  }
}

// ---------------- GCN aggregation: wave-per-node, uint4 gathers ----------------
template<int OUT_BF16, int DO_RELU>
__global__ __launch_bounds__(256) void k_agg(const float* __restrict__ bias,
                                             void* __restrict__ outv) {
  const int t = threadIdx.x, w = t >> 6, lane = t & 63;
  const int i = blockIdx.x*4 + w;
  const int d = lane * 8;
  const uint4* tbl = (const uint4*)g_hsh;
  float a[8] = {0,0,0,0,0,0,0,0};
  acc8(tbl[i*64 + lane], a);
  int e0 = g_off[i], e1 = g_off[i+1];
  int e = e0;
  for (; e + 4 <= e1; e += 4) {
    int s0 = g_adj[e+0], s1 = g_adj[e+1], s2 = g_adj[e+2], s3 = g_adj[e+3];
    uint4 v0 = tbl[s0*64 + lane];
    uint4 v1 = tbl[s1*64 + lane];
    uint4 v2 = tbl[s2*64 + lane];
    uint4 v3 = tbl[s3*64 + lane];
    acc8(v0, a); acc8(v1, a); acc8(v2, a); acc8(v3, a);
  }
  for (; e < e1; e++) acc8(tbl[g_adj[e]*64 + lane], a);
  float di = g_dinv[i];
  const float4 b0 = *(const float4*)&bias[d];
  const float4 b1 = *(const float4*)&bias[d+4];
  a[0]=di*a[0]+b0.x; a[1]=di*a[1]+b0.y; a[2]=di*a[2]+b0.z; a[3]=di*a[3]+b0.w;
  a[4]=di*a[4]+b1.x; a[5]=di*a[5]+b1.y; a[6]=di*a[6]+b1.z; a[7]=di*a[7]+b1.w;
  if (DO_RELU) {
    #pragma unroll
    for (int q = 0; q < 8; q++) a[q] = fmaxf(a[q], 0.f);
  }
  if (OUT_BF16) {
    uint4 r;
    r.x = ((u32)f2bf(a[1])<<16) | f2bf(a[0]);
    r.y = ((u32)f2bf(a[3])<<16) | f2bf(a[2]);
    r.z = ((u32)f2bf(a[5])<<16) | f2bf(a[4]);
    r.w = ((u32)f2bf(a[7])<<16) | f2bf(a[6]);
    *(uint4*)&((u16*)outv)[i*512 + d] = r;
  } else {
    float4 r0; r0.x=a[0]; r0.y=a[1]; r0.z=a[2]; r0.w=a[3];
    float4 r1; r1.x=a[4]; r1.y=a[5]; r1.z=a[6]; r1.w=a[7];
    *(float4*)&((float*)outv)[i*512 + d]     = r0;
    *(float4*)&((float*)outv)[i*512 + d + 4] = r1;
  }
}

// ---------------- host ----------------
static float* symf(const void* s) { void* p = nullptr; (void)hipGetSymbolAddress(&p, s); return (float*)p; }

extern "C" void kernel_launch(void* const* d_in, const int* in_sizes, int n_in,
                              void* d_out, int out_size, void* d_ws, size_t ws_size,
                              hipStream_t stream) {
  const float* feat = (const float*)d_in[0];
  const int*   edges= (const int*)  d_in[1];
  const float* linw = (const float*)d_in[2];
  const float* linb = (const float*)d_in[3];
  const float* ipw  = (const float*)d_in[4];
  const float* ipb  = (const float*)d_in[5];
  const float* outw = (const float*)d_in[6];
  const float* outb = (const float*)d_in[7];
  const float* ln1g = (const float*)d_in[8];
  const float* ln1b = (const float*)d_in[9];
  const float* fw1  = (const float*)d_in[10];
  const float* fb1  = (const float*)d_in[11];
  const float* fw2  = (const float*)d_in[12];
  const float* fb2  = (const float*)d_in[13];
  const float* ln2g = (const float*)d_in[14];
  const float* ln2b = (const float*)d_in[15];
  const float* W1g  = (const float*)d_in[16];
  const float* b1g  = (const float*)d_in[17];
  const float* W2g  = (const float*)d_in[18];
  const float* b2g  = (const float*)d_in[19];
  const float* W3g  = (const float*)d_in[20];
  const float* b3g  = (const float*)d_in[21];
  const float* W4g  = (const float*)d_in[22];
  const float* b4g  = (const float*)d_in[23];
  float* out = (float*)d_out;

  u16*   p_h1h = (u16*)symf(HIP_SYMBOL(g_h1h));
  float* p_ff  = symf(HIP_SYMBOL(g_ff));
  u16*   p_xmh = (u16*)symf(HIP_SYMBOL(g_xmh));
  u16*   p_hsh = (u16*)symf(HIP_SYMBOL(g_hsh));
  u16*   p_xgh = (u16*)symf(HIP_SYMBOL(g_xgh));
  u16*   p_wbf = (u16*)symf(HIP_SYMBOL(g_wbf));
  float* p_dinv= symf(HIP_SYMBOL(g_dinv));

  // fused prep pipeline
  k_fuse1<<<20,   256, 0, stream>>>(ipw, ipb, linw, linb);
  k_fuse2<<<257,  256, 0, stream>>>(outw, outb, linw, linb, ln1g, ln1b, edges);
  k_fuse3<<<1953, 256, 0, stream>>>(feat, fw1, fw2, W1g, W2g, W3g, W4g);
  k_fuse4<<<768,  256, 0, stream>>>(feat, fb1, edges);

  // FFN2: ff = h1 @ W2^T + b2 (bf16 MFMA, fp32 out)
  k_mm64<0,0,1><<<dim3(256/64, NT/64), 256, 0, stream>>>(
      p_h1h, p_wbf + OFF_W2, p_ff, NT, 256, 2048, nullptr, fb2);
  k_ln2<<<NN, 256, 0, stream>>>(ln2g, ln2b);

  // GCN layers
  k_mm64<1,1,0><<<dim3(8, 32), 256, 0, stream>>>(
      p_xmh, p_wbf + OFF_G1, p_hsh, NN, 512, 256, p_dinv, nullptr);
  k_agg<1,1><<<NN/4, 256, 0, stream>>>(b1g, p_xgh);
  k_mm64<1,1,0><<<dim3(8, 32), 256, 0, stream>>>(
      p_xgh, p_wbf + OFF_G2, p_hsh, NN, 512, 512, p_dinv, nullptr);
  k_agg<1,1><<<NN/4, 256, 0, stream>>>(b2g, p_xgh);
  k_mm64<1,1,0><<<dim3(8, 32), 256, 0, stream>>>(
      p_xgh, p_wbf + OFF_G3, p_hsh, NN, 512, 512, p_dinv, nullptr);
  k_agg<1,1><<<NN/4, 256, 0, stream>>>(b3g, p_xgh);
  k_mm64<1,1,0><<<dim3(8, 32), 256, 0, stream>>>(
      p_xgh, p_wbf + OFF_G4, p_hsh, NN, 512, 512, p_dinv, nullptr);
  k_agg<0,0><<<NN/4, 256, 0, stream>>>(b4g, out);
}

// Round 7
// 183.079 us; speedup vs baseline: 2.3422x; 1.1075x over previous
//
#include <hip/hip_runtime.h>
#include <hip/hip_bf16.h>
#include <math.h>

// Problem constants
#define NN   2048
#define FB   4
#define DD   256
#define EE   65536
#define NT   (NN*FB)
#define FFD  2048

typedef unsigned int u32;
typedef unsigned short u16;
typedef __attribute__((ext_vector_type(4))) float f32x4;
typedef __attribute__((ext_vector_type(8))) short bf16x8;

// weight buffer offsets (bf16 elements)
#define OFF_W2   0
#define OFF_G1   524288
#define OFF_G2   655360
#define OFF_G3   917504
#define OFF_G4   1179648
#define WBF_TOT  1441792

// ---------------- static device scratch ----------------
__device__ float g_A[768], g_B[768];
__device__ float g_coefA[4], g_coefC[4];
__device__ float g_meanv[6], g_G[36];
__device__ float g_Vx[8*DD];
__device__ float g_W1V[FFD*8];
__device__ float g_m[NT*4];
__device__ float g_cc[NT*8];                // per-token LN1 coefficients
__device__ u16   g_h1h[(size_t)NT*FFD];     // h1 in bf16 (32 MB)
__device__ float g_ff[NT*DD];
__device__ u16   g_xmh[NN*DD];              // GCN input bf16
__device__ u16   g_hsh[NN*512];             // per-layer transformed bf16 (2 MB, L2-resident)
__device__ u16   g_xgh[NN*512];             // per-layer activations bf16
__device__ u16   g_wbf[WBF_TOT];            // all GEMM weights bf16
// line-padded atomic counters: 1 counter per 64B cache line (16 ints)
__device__ __align__(64) int g_degp[NN*16];
__device__ __align__(64) int g_curp[NN*16];
__device__ int   g_off[NN+1], g_adj[EE];
__device__ float g_dinv[NN];

// ---------------- helpers ----------------
__device__ __forceinline__ u16 f2bf(float x) {
  u32 u = __float_as_uint(x);
  return (u16)((u + 0x7FFFu + ((u >> 16) & 1u)) >> 16);
}
__device__ __forceinline__ float bf2f(u16 x) {
  return __uint_as_float(((u32)x) << 16);
}
__device__ __forceinline__ void gl_lds16(const void* g, void* l) {
  __builtin_amdgcn_global_load_lds(
      (const __attribute__((address_space(1))) u32*)g,
      (__attribute__((address_space(3))) u32*)l, 16, 0, 0);
}
__device__ __forceinline__ float qred(float v) {   // reduce across 4-lane quad
  v += __shfl_xor(v, 1, 64);
  v += __shfl_xor(v, 2, 64);
  return v;
}
__device__ __forceinline__ void acc8(const uint4 v, float* a) {
  a[0]+=__uint_as_float(v.x<<16); a[1]+=__uint_as_float(v.x&0xffff0000u);
  a[2]+=__uint_as_float(v.y<<16); a[3]+=__uint_as_float(v.y&0xffff0000u);
  a[4]+=__uint_as_float(v.z<<16); a[5]+=__uint_as_float(v.z&0xffff0000u);
  a[6]+=__uint_as_float(v.w<<16); a[7]+=__uint_as_float(v.w&0xffff0000u);
}

// ========= FUSE-1: prep_ab (blk 0..11)  ||  zero padded counters (blk 12..139) =========
__global__ __launch_bounds__(256) void k_fuse1(const float* __restrict__ ipw,
    const float* __restrict__ ipb, const float* __restrict__ linw,
    const float* __restrict__ linb) {
  __shared__ __align__(16) float sm[512];
  const int b = blockIdx.x, t = threadIdx.x;
  if (b < 12) {
    float* lw = sm; float* lb = sm + 256;
    lw[t] = linw[t]; lb[t] = linb[t];
    __syncthreads();
    int j = b*64 + (t>>2), c = t&3;
    const float4* row = (const float4*)&ipw[j*256 + c*64];
    float a = 0.f, bb = 0.f;
    #pragma unroll
    for (int q = 0; q < 16; q++) {
      float4 v = row[q]; int d0 = c*64 + q*4;
      a  += v.x*lw[d0] + v.y*lw[d0+1] + v.z*lw[d0+2] + v.w*lw[d0+3];
      bb += v.x*lb[d0] + v.y*lb[d0+1] + v.z*lb[d0+2] + v.w*lb[d0+3];
    }
    a = qred(a); bb = qred(bb);
    if (c == 0) { g_A[j] = a; g_B[j] = bb + ipb[j]; }
  } else {
    int i = (b - 12)*256 + t;
    if (i < NN*16) { g_degp[i] = 0; g_curp[i] = 0; }
  }
}

// ================= FUSE-2: prep_head (blk 0)  ||  deg (blk 1..256) =================
__global__ __launch_bounds__(256) void k_fuse2(const float* __restrict__ outw,
    const float* __restrict__ outb, const float* __restrict__ linw,
    const float* __restrict__ linb, const float* __restrict__ g1,
    const float* __restrict__ b1ln, const int* __restrict__ edges) {
  __shared__ __align__(16) float sm[512 + 4*27];
  const int b = blockIdx.x, t = threadIdx.x;
  if (b == 0) {
    int lane = t & 63, w = t >> 6;
    {
      float aq = g_A[w*64 + lane], ak = g_A[256 + w*64 + lane], bq = g_B[w*64 + lane];
      float pa = aq * ak, pc = bq * ak;
      #pragma unroll
      for (int o = 32; o > 0; o >>= 1) { pa += __shfl_down(pa, o, 64); pc += __shfl_down(pc, o, 64); }
      if (lane == 0) { g_coefA[w] = pa * 0.125f; g_coefC[w] = pc * 0.125f; }
    }
    float* A2 = sm; float* B2 = sm + 256; float* wred = sm + 512;
    A2[t] = g_A[512 + t]; B2[t] = g_B[512 + t];
    __syncthreads();
    const int d = t;
    const float4* row = (const float4*)&outw[d*256];
    float pv[4] = {0,0,0,0}, q0 = 0.f;
    #pragma unroll 8
    for (int q = 0; q < 64; q++) {
      float4 v = row[q]; int e0 = q*4; int h = q >> 4;
      pv[h] += v.x*A2[e0] + v.y*A2[e0+1] + v.z*A2[e0+2] + v.w*A2[e0+3];
      q0    += v.x*B2[e0] + v.y*B2[e0+1] + v.z*B2[e0+2] + v.w*B2[e0+3];
    }
    q0 += outb[d];
    float c0 = linb[d] + q0;
    float Mv[6] = { linw[d], pv[0], pv[1], pv[2], pv[3], c0 };
    float vals[27];
    { int idx = 0;
      #pragma unroll
      for (int k = 0; k < 6; k++) vals[idx++] = Mv[k];
      #pragma unroll
      for (int k = 0; k < 6; k++)
        #pragma unroll
        for (int l = 0; l < 6; l++) if (l >= k) vals[idx++] = Mv[k]*Mv[l];
    }
    #pragma unroll
    for (int k2 = 0; k2 < 27; k2++) {
      float v = vals[k2];
      #pragma unroll
      for (int o = 32; o > 0; o >>= 1) v += __shfl_down(v, o, 64);
      if (lane == 0) wred[w*27 + k2] = v;
    }
    __syncthreads();
    if (t < 27) {
      float s = wred[t] + wred[27 + t] + wred[54 + t] + wred[81 + t];
      if (t < 6) g_meanv[t] = s * (1.f/256.f);
      else {
        int p = t - 6, k = 0;
        while (p >= 6 - k) { p -= 6 - k; k++; }
        int l = k + p;
        g_G[k*6+l] = s; g_G[l*6+k] = s;
      }
    }
    #pragma unroll
    for (int k = 0; k < 6; k++) g_Vx[k*256 + d] = Mv[k] * g1[d];
    g_Vx[6*256 + d] = g1[d];
    g_Vx[7*256 + d] = b1ln[d];
  } else {
    int e = (b - 1)*256 + t;
    atomicAdd(&g_degp[edges[EE + e] * 16], 1);
  }
}

// ===== FUSE-3: attn_m (blk 0..511) || w1v (512..543) || scan (544) || cvt (545..1952) =====
__global__ __launch_bounds__(256) void k_fuse3(const float* __restrict__ feat,
    const float* __restrict__ w1,
    const float* __restrict__ w2c, const float* __restrict__ W1c,
    const float* __restrict__ W2c, const float* __restrict__ W3c,
    const float* __restrict__ W4c) {
  __shared__ __align__(16) char smraw[34816];
  const int b = blockIdx.x, t = threadIdx.x;
  if (b < 512) {
    // ---- attn_m ----
    float* fs = (float*)smraw;                 // [4][2048]
    float* ss = fs + 8192;                     // [64][4]
    float* ww = ss + 256;                      // [64][4]
    for (int i = t; i < 2048; i += 256) {
      const float4 v = *(const float4*)&feat[i*4];
      fs[0*2048+i] = v.x; fs[1*2048+i] = v.y; fs[2*2048+i] = v.z; fs[3*2048+i] = v.w;
    }
    __syncthreads();
    int tuple = b * 64 + (t >> 2);
    int c = t & 3;
    int h = tuple & 3, f = (tuple >> 2) & 3, n = tuple >> 4;
    float fi = fs[f*2048 + n];
    float tt = g_coefA[h] * fi + g_coefC[h];
    float s = 0.f, wsum = 0.f;
    int j0 = c * 512;
    for (int j = j0; j < j0 + 512; j++) {
      float fj = fs[f*2048 + j];
      float e = __expf(tt * fj);
      s += e; wsum += e * fj;
    }
    ss[(t>>2)*4 + c] = s; ww[(t>>2)*4 + c] = wsum;
    __syncthreads();
    if (c == 0) {
      float S = ss[(t>>2)*4] + ss[(t>>2)*4+1] + ss[(t>>2)*4+2] + ss[(t>>2)*4+3];
      float W = ww[(t>>2)*4] + ww[(t>>2)*4+1] + ww[(t>>2)*4+2] + ww[(t>>2)*4+3];
      g_m[tuple] = W / S;
    }
  } else if (b < 544) {
    // ---- w1v: W1V[j][k] = W1[j,:]·Vx_k ----
    float* vx = (float*)smraw;                 // [8][256]
    #pragma unroll
    for (int k = 0; k < 8; k++) vx[k*256 + t] = g_Vx[k*256 + t];
    __syncthreads();
    int j = (b - 512)*64 + (t>>2), c = t&3;
    const float4* row = (const float4*)&w1[j*256 + c*64];
    float acc[8] = {0,0,0,0,0,0,0,0};
    #pragma unroll
    for (int q = 0; q < 16; q++) {
      float4 v = row[q]; int d0 = c*64 + q*4;
      #pragma unroll
      for (int k = 0; k < 8; k++)
        acc[k] += v.x*vx[k*256+d0] + v.y*vx[k*256+d0+1]
                + v.z*vx[k*256+d0+2] + v.w*vx[k*256+d0+3];
    }
    #pragma unroll
    for (int k = 0; k < 8; k++) acc[k] = qred(acc[k]);
    if (c == 0) {
      #pragma unroll
      for (int k = 0; k < 8; k++) g_W1V[j*8 + k] = acc[k];
    }
  } else if (b == 544) {
    // ---- scan (reads padded deg counters) ----
    int* wt = (int*)smraw;
    int base = t * 8;
    int v[8], ex[8], sum = 0;
    #pragma unroll
    for (int i = 0; i < 8; i++) { ex[i] = sum; v[i] = g_degp[(base+i)*16]; sum += v[i]; }
    int lane = t & 63, w = t >> 6;
    int inc = sum;
    #pragma unroll
    for (int o = 1; o < 64; o <<= 1) { int x = __shfl_up(inc, o, 64); if (lane >= o) inc += x; }
    if (lane == 63) wt[w] = inc;
    __syncthreads();
    int wb = 0;
    for (int j = 0; j < w; j++) wb += wt[j];
    int excl = wb + inc - sum;
    #pragma unroll
    for (int i = 0; i < 8; i++) {
      g_off[base+i] = excl + ex[i];
      g_dinv[base+i] = rsqrtf((float)(v[i] + 1));
    }
    if (t == 255) g_off[NN] = wb + inc;
  } else {
    // ---- cvt all weights ----
    int i = ((b - 545)*256 + t) * 4;
    const float* src; int off;
    if (i < OFF_G1)      { src = w2c; off = OFF_W2; }
    else if (i < OFF_G2) { src = W1c; off = OFF_G1; }
    else if (i < OFF_G3) { src = W2c; off = OFF_G2; }
    else if (i < OFF_G4) { src = W3c; off = OFF_G3; }
    else                 { src = W4c; off = OFF_G4; }
    float4 v = *(const float4*)&src[i - off];
    ushort4 r;
    r.x = f2bf(v.x); r.y = f2bf(v.y); r.z = f2bf(v.z); r.w = f2bf(v.w);
    *(ushort4*)&g_wbf[i] = r;
  }
}

// ================= FUSE-4: token/h1 (blk 0..511)  ||  fill (512..767) =================
__global__ __launch_bounds__(256) void k_fuse4(const float* __restrict__ feat,
    const float* __restrict__ fb1, const int* __restrict__ edges) {
  __shared__ __align__(16) float cc[16*8];
  const int b = blockIdx.x, t = threadIdx.x;
  if (b < 512) {
    if (t < 16) {
      int tok = b * 16 + t;
      int n = tok >> 2, f = tok & 3;
      float fi = feat[n*4 + f];
      float u[6] = { fi, g_m[tok*4+0], g_m[tok*4+1], g_m[tok*4+2], g_m[tok*4+3], 1.f };
      float mu = 0.f;
      #pragma unroll
      for (int k = 0; k < 6; k++) mu += g_meanv[k] * u[k];
      float q = 0.f;
      for (int k = 0; k < 6; k++)
        for (int l = 0; l < 6; l++) q += u[k] * g_G[k*6+l] * u[l];
      q *= (1.f/256.f);
      float var = q - mu * mu;
      float s = rsqrtf(var + 1e-5f);
      float c0=fi*s, c1=u[1]*s, c2=u[2]*s, c3=u[3]*s, c4=u[4]*s, c5=s, c6=-mu*s, c7=1.f;
      cc[t*8+0]=c0; cc[t*8+1]=c1; cc[t*8+2]=c2; cc[t*8+3]=c3;
      cc[t*8+4]=c4; cc[t*8+5]=c5; cc[t*8+6]=c6; cc[t*8+7]=c7;
      float4 w0; w0.x=c0; w0.y=c1; w0.z=c2; w0.w=c3;
      float4 w1v; w1v.x=c4; w1v.y=c5; w1v.z=c6; w1v.w=c7;
      *(float4*)&g_cc[tok*8]     = w0;
      *(float4*)&g_cc[tok*8 + 4] = w1v;
    }
    __syncthreads();
    const int j0 = t * 8;
    float w[8][8];
    #pragma unroll
    for (int q = 0; q < 8; q++) {
      float4 a0 = *(const float4*)&g_W1V[(j0+q)*8];
      float4 a1 = *(const float4*)&g_W1V[(j0+q)*8 + 4];
      w[q][0]=a0.x; w[q][1]=a0.y; w[q][2]=a0.z; w[q][3]=a0.w;
      w[q][4]=a1.x; w[q][5]=a1.y; w[q][6]=a1.z; w[q][7]=a1.w;
    }
    float bv[8];
    { float4 b0 = *(const float4*)&fb1[j0];
      float4 b1 = *(const float4*)&fb1[j0+4];
      bv[0]=b0.x; bv[1]=b0.y; bv[2]=b0.z; bv[3]=b0.w;
      bv[4]=b1.x; bv[5]=b1.y; bv[6]=b1.z; bv[7]=b1.w; }
    const int tok0 = b * 16;
    for (int tk = 0; tk < 16; tk++) {
      float c0=cc[tk*8+0], c1=cc[tk*8+1], c2=cc[tk*8+2], c3=cc[tk*8+3];
      float c4=cc[tk*8+4], c5=cc[tk*8+5], c6=cc[tk*8+6], c7=cc[tk*8+7];
      u16 h[8];
      #pragma unroll
      for (int q = 0; q < 8; q++) {
        float v = bv[q] + c0*w[q][0] + c1*w[q][1] + c2*w[q][2] + c3*w[q][3]
                        + c4*w[q][4] + c5*w[q][5] + c6*w[q][6] + c7*w[q][7];
        h[q] = f2bf(fmaxf(v, 0.f));
      }
      uint4 r;
      r.x = ((u32)h[1]<<16) | h[0];
      r.y = ((u32)h[3]<<16) | h[2];
      r.z = ((u32)h[5]<<16) | h[4];
      r.w = ((u32)h[7]<<16) | h[6];
      *(uint4*)&g_h1h[(size_t)(tok0 + tk)*2048 + j0] = r;
    }
  } else {
    int e = (b - 512)*256 + t;
    int s = edges[e], d = edges[EE + e];
    int pos = atomicAdd(&g_curp[d*16], 1);
    g_adj[g_off[d] + pos] = s;
  }
}

// ---------------- bf16 MFMA GEMM: C[M,N] = A[M,K] @ B[N,K]^T ----------------
template<int DO_ROWSCALE, int OUT_BF16, int HAS_BIAS>
__global__ __launch_bounds__(256) void k_mm64(
    const u16* __restrict__ A, const u16* __restrict__ Bm, void* __restrict__ Cv,
    int M, int N, int K,
    const float* __restrict__ rowscale, const float* __restrict__ bias)
{
  __shared__ u16 Asl[64*64];
  __shared__ u16 Bsl[64*64];
  const int t = threadIdx.x;
  const int w = t >> 6, lane = t & 63;
  const int bm = blockIdx.y * 64, bn = blockIdx.x * 64;
  const int wr = w >> 1, wc = w & 1;
  const int fr = lane & 15;
  const int gk = lane >> 4;
  const int sslot = lane & 7;
  f32x4 acc[2][2] = {};
  for (int k0 = 0; k0 < K; k0 += 64) {
    #pragma unroll
    for (int c = 0; c < 2; c++) {
      int r = (w << 4) + (c << 3) + (lane >> 3);
      int ks = ((sslot ^ (r & 7)) << 3);
      gl_lds16(A  + (size_t)(bm + r)*K + k0 + ks, Asl + (w << 10) + (c << 9));
      gl_lds16(Bm + (size_t)(bn + r)*K + k0 + ks, Bsl + (w << 10) + (c << 9));
    }
    __syncthreads();
    bf16x8 af[2][2], bfv[2][2];
    #pragma unroll
    for (int rb = 0; rb < 2; rb++) {
      int row = wr*32 + rb*16 + fr;
      #pragma unroll
      for (int kk = 0; kk < 2; kk++) {
        int q = (kk << 2) + gk;
        af[rb][kk] = *(const bf16x8*)&Asl[(row << 6) + ((q ^ (row & 7)) << 3)];
      }
    }
    #pragma unroll
    for (int nb = 0; nb < 2; nb++) {
      int col = wc*32 + nb*16 + fr;
      #pragma unroll
      for (int kk = 0; kk < 2; kk++) {
        int q = (kk << 2) + gk;
        bfv[nb][kk] = *(const bf16x8*)&Bsl[(col << 6) + ((q ^ (col & 7)) << 3)];
      }
    }
    #pragma unroll
    for (int kk = 0; kk < 2; kk++)
      #pragma unroll
      for (int rb = 0; rb < 2; rb++)
        #pragma unroll
        for (int nb = 0; nb < 2; nb++)
          acc[rb][nb] = __builtin_amdgcn_mfma_f32_16x16x32_bf16(af[rb][kk], bfv[nb][kk], acc[rb][nb], 0, 0, 0);
    __syncthreads();
  }
  #pragma unroll
  for (int rb = 0; rb < 2; rb++) {
    #pragma unroll
    for (int r = 0; r < 4; r++) {
      int row = bm + wr*32 + rb*16 + gk*4 + r;
      float rs = DO_ROWSCALE ? rowscale[row] : 1.f;
      #pragma unroll
      for (int nb = 0; nb < 2; nb++) {
        int col = bn + wc*32 + nb*16 + fr;
        float v = acc[rb][nb][r];
        if (HAS_BIAS) v += bias[col];
        if (DO_ROWSCALE) v *= rs;
        if (OUT_BF16) ((u16*)Cv)[(size_t)row*N + col] = f2bf(v);
        else ((float*)Cv)[(size_t)row*N + col] = v;
      }
    }
  }
}

// ---------------- K6: LN2 + mean + relu -> bf16 (wave-per-f, 2 barriers) ----------------
__global__ __launch_bounds__(256) void k_ln2(const float* __restrict__ g2,
                                             const float* __restrict__ b2ln) {
  __shared__ __align__(16) float vx[2048];
  __shared__ __align__(16) float xs[4*256];
  const int n = blockIdx.x, t = threadIdx.x;
  #pragma unroll
  for (int k = 0; k < 8; k++) vx[k*256 + t] = g_Vx[k*256 + t];
  __syncthreads();
  const int f = t >> 6, lane = t & 63;
  const int tok = n*4 + f;
  const int d0 = lane * 4;
  float c[8];
  { float4 c0 = *(const float4*)&g_cc[tok*8];
    float4 c1 = *(const float4*)&g_cc[tok*8 + 4];
    c[0]=c0.x; c[1]=c0.y; c[2]=c0.z; c[3]=c0.w;
    c[4]=c1.x; c[5]=c1.y; c[6]=c1.z; c[7]=c1.w; }
  float4 ffv = *(const float4*)&g_ff[tok*256 + d0];
  float v[4];
  #pragma unroll
  for (int j = 0; j < 4; j++) {
    float x1 = 0.f;
    #pragma unroll
    for (int k = 0; k < 8; k++) x1 += c[k] * vx[k*256 + d0 + j];
    v[j] = x1;
  }
  v[0] += ffv.x; v[1] += ffv.y; v[2] += ffv.z; v[3] += ffv.w;
  float s1 = v[0]+v[1]+v[2]+v[3];
  float s2 = v[0]*v[0]+v[1]*v[1]+v[2]*v[2]+v[3]*v[3];
  #pragma unroll
  for (int o = 32; o > 0; o >>= 1) { s1 += __shfl_down(s1, o, 64); s2 += __shfl_down(s2, o, 64); }
  s1 = __shfl(s1, 0, 64); s2 = __shfl(s2, 0, 64);
  float mu = s1 * (1.f/256.f);
  float var = s2 * (1.f/256.f) - mu*mu;
  float inv = rsqrtf(var + 1e-5f);
  float4 gg = *(const float4*)&g2[d0];
  float4 bb = *(const float4*)&b2ln[d0];
  float4 x2;
  x2.x = (v[0]-mu)*inv*gg.x + bb.x;
  x2.y = (v[1]-mu)*inv*gg.y + bb.y;
  x2.z = (v[2]-mu)*inv*gg.z + bb.z;
  x2.w = (v[3]-mu)*inv*gg.w + bb.w;
  *(float4*)&xs[f*256 + d0] = x2;
  __syncthreads();
  if (t < 64) {
    int dd = t * 4;
    float4 a0 = *(const float4*)&xs[0*256 + dd];
    float4 a1 = *(const float4*)&xs[1*256 + dd];
    float4 a2 = *(const float4*)&xs[2*256 + dd];
    float4 a3 = *(const float4*)&xs[3*256 + dd];
    float r0 = fmaxf((a0.x+a1.x+a2.x+a3.x)*0.25f, 0.f);
    float r1 = fmaxf((a0.y+a1.y+a2.y+a3.y)*0.25f, 0.f);
    float r2 = fmaxf((a0.z+a1.z+a2.z+a3.z)*0.25f, 0.f);
    float r3 = fmaxf((a0.w+a1.w+a2.w+a3.w)*0.25f, 0.f);
    ushort4 r;
    r.x = f2bf(r0); r.y = f2bf(r1); r.z = f2bf(r2); r.w = f2bf(r3);
    *(ushort4*)&g_xmh[n*256 + dd] = r;
  }
}

// ---------------- GCN aggregation: wave-per-node, uint4 gathers ----------------
template<int OUT_BF16, int DO_RELU>
__global__ __launch_bounds__(256) void k_agg(const float* __restrict__ bias,
                                             void* __restrict__ outv) {
  const int t = threadIdx.x, w = t >> 6, lane = t & 63;
  const int i = blockIdx.x*4 + w;
  const int d = lane * 8;
  const uint4* tbl = (const uint4*)g_hsh;
  float a[8] = {0,0,0,0,0,0,0,0};
  acc8(tbl[i*64 + lane], a);
  int e0 = g_off[i], e1 = g_off[i+1];
  int e = e0;
  for (; e + 4 <= e1; e += 4) {
    int s0 = g_adj[e+0], s1 = g_adj[e+1], s2 = g_adj[e+2], s3 = g_adj[e+3];
    uint4 v0 = tbl[s0*64 + lane];
    uint4 v1 = tbl[s1*64 + lane];
    uint4 v2 = tbl[s2*64 + lane];
    uint4 v3 = tbl[s3*64 + lane];
    acc8(v0, a); acc8(v1, a); acc8(v2, a); acc8(v3, a);
  }
  for (; e < e1; e++) acc8(tbl[g_adj[e]*64 + lane], a);
  float di = g_dinv[i];
  const float4 b0 = *(const float4*)&bias[d];
  const float4 b1 = *(const float4*)&bias[d+4];
  a[0]=di*a[0]+b0.x; a[1]=di*a[1]+b0.y; a[2]=di*a[2]+b0.z; a[3]=di*a[3]+b0.w;
  a[4]=di*a[4]+b1.x; a[5]=di*a[5]+b1.y; a[6]=di*a[6]+b1.z; a[7]=di*a[7]+b1.w;
  if (DO_RELU) {
    #pragma unroll
    for (int q = 0; q < 8; q++) a[q] = fmaxf(a[q], 0.f);
  }
  if (OUT_BF16) {
    uint4 r;
    r.x = ((u32)f2bf(a[1])<<16) | f2bf(a[0]);
    r.y = ((u32)f2bf(a[3])<<16) | f2bf(a[2]);
    r.z = ((u32)f2bf(a[5])<<16) | f2bf(a[4]);
    r.w = ((u32)f2bf(a[7])<<16) | f2bf(a[6]);
    *(uint4*)&((u16*)outv)[i*512 + d] = r;
  } else {
    float4 r0; r0.x=a[0]; r0.y=a[1]; r0.z=a[2]; r0.w=a[3];
    float4 r1; r1.x=a[4]; r1.y=a[5]; r1.z=a[6]; r1.w=a[7];
    *(float4*)&((float*)outv)[i*512 + d]     = r0;
    *(float4*)&((float*)outv)[i*512 + d + 4] = r1;
  }
}

// ---------------- host ----------------
static float* symf(const void* s) { void* p = nullptr; (void)hipGetSymbolAddress(&p, s); return (float*)p; }

extern "C" void kernel_launch(void* const* d_in, const int* in_sizes, int n_in,
                              void* d_out, int out_size, void* d_ws, size_t ws_size,
                              hipStream_t stream) {
  const float* feat = (const float*)d_in[0];
  const int*   edges= (const int*)  d_in[1];
  const float* linw = (const float*)d_in[2];
  const float* linb = (const float*)d_in[3];
  const float* ipw  = (const float*)d_in[4];
  const float* ipb  = (const float*)d_in[5];
  const float* outw = (const float*)d_in[6];
  const float* outb = (const float*)d_in[7];
  const float* ln1g = (const float*)d_in[8];
  const float* ln1b = (const float*)d_in[9];
  const float* fw1  = (const float*)d_in[10];
  const float* fb1  = (const float*)d_in[11];
  const float* fw2  = (const float*)d_in[12];
  const float* fb2  = (const float*)d_in[13];
  const float* ln2g = (const float*)d_in[14];
  const float* ln2b = (const float*)d_in[15];
  const float* W1g  = (const float*)d_in[16];
  const float* b1g  = (const float*)d_in[17];
  const float* W2g  = (const float*)d_in[18];
  const float* b2g  = (const float*)d_in[19];
  const float* W3g  = (const float*)d_in[20];
  const float* b3g  = (const float*)d_in[21];
  const float* W4g  = (const float*)d_in[22];
  const float* b4g  = (const float*)d_in[23];
  float* out = (float*)d_out;

  u16*   p_h1h = (u16*)symf(HIP_SYMBOL(g_h1h));
  float* p_ff  = symf(HIP_SYMBOL(g_ff));
  u16*   p_xmh = (u16*)symf(HIP_SYMBOL(g_xmh));
  u16*   p_hsh = (u16*)symf(HIP_SYMBOL(g_hsh));
  u16*   p_xgh = (u16*)symf(HIP_SYMBOL(g_xgh));
  u16*   p_wbf = (u16*)symf(HIP_SYMBOL(g_wbf));
  float* p_dinv= symf(HIP_SYMBOL(g_dinv));

  // fused prep pipeline
  k_fuse1<<<140,  256, 0, stream>>>(ipw, ipb, linw, linb);
  k_fuse2<<<257,  256, 0, stream>>>(outw, outb, linw, linb, ln1g, ln1b, edges);
  k_fuse3<<<1953, 256, 0, stream>>>(feat, fw1, fw2, W1g, W2g, W3g, W4g);
  k_fuse4<<<768,  256, 0, stream>>>(feat, fb1, edges);

  // FFN2: ff = h1 @ W2^T + b2 (bf16 MFMA, fp32 out)
  k_mm64<0,0,1><<<dim3(256/64, NT/64), 256, 0, stream>>>(
      p_h1h, p_wbf + OFF_W2, p_ff, NT, 256, 2048, nullptr, fb2);
  k_ln2<<<NN, 256, 0, stream>>>(ln2g, ln2b);

  // GCN layers
  k_mm64<1,1,0><<<dim3(8, 32), 256, 0, stream>>>(
      p_xmh, p_wbf + OFF_G1, p_hsh, NN, 512, 256, p_dinv, nullptr);
  k_agg<1,1><<<NN/4, 256, 0, stream>>>(b1g, p_xgh);
  k_mm64<1,1,0><<<dim3(8, 32), 256, 0, stream>>>(
      p_xgh, p_wbf + OFF_G2, p_hsh, NN, 512, 512, p_dinv, nullptr);
  k_agg<1,1><<<NN/4, 256, 0, stream>>>(b2g, p_xgh);
  k_mm64<1,1,0><<<dim3(8, 32), 256, 0, stream>>>(
      p_xgh, p_wbf + OFF_G3, p_hsh, NN, 512, 512, p_dinv, nullptr);
  k_agg<1,1><<<NN/4, 256, 0, stream>>>(b3g, p_xgh);
  k_mm64<1,1,0><<<dim3(8, 32), 256, 0, stream>>>(
      p_xgh, p_wbf + OFF_G4, p_hsh, NN, 512, 512, p_dinv, nullptr);
  k_agg<0,0><<<NN/4, 256, 0, stream>>>(b4g, out);
}